// Round 6
// baseline (2024.810 us; speedup 1.0000x reference)
//
#include <hip/hip_runtime.h>
#include <hip/hip_bf16.h>

typedef __attribute__((ext_vector_type(8))) short short8;   // 8 bf16 (4 VGPRs) — MFMA A/B frag
typedef __attribute__((ext_vector_type(4))) float f32x4;    // MFMA C/D frag

#define DDIM 256
#define WROW 257
#define WSTRIDE 66049  // 257*257

__device__ __forceinline__ unsigned short f2bf(float f) {
    unsigned int u = __float_as_uint(f);
    u += 0x7fff + ((u >> 16) & 1);   // RNE (finite values)
    return (unsigned short)(u >> 16);
}
__device__ __forceinline__ float bf2f(unsigned short s) {
    return __uint_as_float(((unsigned int)s) << 16);
}

// ======================= FAST PATH =======================

// Symmetrized, pre-scaled, transposed W (unchanged from R5):
//   Wt2[n][j][k] = s * (A[k][j] + A[j][k]),  s = 1 for k32<j32, 0.5 for k32==j32
__global__ __launch_bounds__(256) void conv_w2_kernel(
    const float* __restrict__ Wf, unsigned short* __restrict__ Wt2)
{
    __shared__ float tKJ[64][65];
    __shared__ float tJK[64][65];
    const int TJ[10] = {0,1,1,2,2,2,3,3,3,3};
    const int TK[10] = {0,0,1,0,1,2,0,1,2,3};
    const int tid = threadIdx.x;
    const int n   = blockIdx.y;
    const int tj  = TJ[blockIdx.x];
    const int tk  = TK[blockIdx.x];
    const float* Wn = Wf + (size_t)n * WSTRIDE;
    #pragma unroll
    for (int it = 0; it < 16; ++it) {
        int r = it * 4 + (tid >> 6);
        int c = tid & 63;
        tKJ[r][c] = Wn[(size_t)(tk * 64 + r) * WROW + tj * 64 + c];
        tJK[r][c] = Wn[(size_t)(tj * 64 + r) * WROW + tk * 64 + c];
    }
    __syncthreads();
    unsigned short* out = Wt2 + ((size_t)n << 16);
    #pragma unroll
    for (int it = 0; it < 8; ++it) {
        int jl = it * 8 + (tid >> 5);
        int k2 = (tid & 31) * 2;
        int p32 = tk * 2 + (k2 >> 5);
        int q32 = tj * 2 + (jl >> 5);
        if (p32 <= q32) {
            float sc = (p32 == q32) ? 0.5f : 1.0f;
            float v0 = sc * (tKJ[k2][jl]     + tJK[jl][k2]);
            float v1 = sc * (tKJ[k2 + 1][jl] + tJK[jl][k2 + 1]);
            unsigned int u = (unsigned)f2bf(v0) | ((unsigned)f2bf(v1) << 16);
            *reinterpret_cast<unsigned int*>(out + (size_t)(tj * 64 + jl) * 256 + tk * 64 + k2) = u;
        }
    }
}

// Vt[n][j] = W[n][j][256] + W[n][256][j];  Dv[n] = W[n][256][256]
__global__ void conv_v_kernel(const float* __restrict__ Wf,
                              float* __restrict__ Vt, float* __restrict__ Dv)
{
    int n = blockIdx.x, j = threadIdx.x;
    const float* Wn = Wf + (size_t)n * WSTRIDE;
    Vt[n * 256 + j] = Wn[(size_t)j * WROW + 256] + Wn[65792 + j];
    if (j == 0) Dv[n] = Wn[66048];
}

// Epilogue gather: Xe2[bt][jt][m][lane] = short8 { x[row(m,qw,r)][jA] r=0..3, x[row][jB] r=0..3 }
//   jA = jt*32 + r15, jB = jA+16, row = m*16 + qw*4 + r (bt-local).  Lane-only-dependent.
__device__ __forceinline__ void xe_gather3(const unsigned short* T, unsigned short* Xe2,
                                           int bx, int tid) {
    const int lane = tid & 63, g = tid >> 6, qw = (tid >> 4) & 3, r15 = tid & 15;
    #pragma unroll
    for (int it = 0; it < 16; ++it) {
        int c  = g * 16 + it;        // flat (h, jt, m) in [0,64)
        int h  = c >> 5;
        int jt = (c >> 2) & 7;
        int m  = c & 3;
        int rbase = h * 64 + m * 16 + qw * 4;
        int jA = jt * 32 + r15;
        unsigned int u0 = T[(rbase + 0) * 256 + jA];
        unsigned int u1 = T[(rbase + 1) * 256 + jA];
        unsigned int u2 = T[(rbase + 2) * 256 + jA];
        unsigned int u3 = T[(rbase + 3) * 256 + jA];
        unsigned int v0 = T[(rbase + 0) * 256 + jA + 16];
        unsigned int v1 = T[(rbase + 1) * 256 + jA + 16];
        unsigned int v2 = T[(rbase + 2) * 256 + jA + 16];
        unsigned int v3 = T[(rbase + 3) * 256 + jA + 16];
        uint4 w = make_uint4(u0 | (u1 << 16), u2 | (u3 << 16),
                             v0 | (v1 << 16), v2 | (v3 << 16));
        *reinterpret_cast<uint4*>(Xe2 + ((size_t)(bx * 2 + h) * 16384 + jt * 2048 + m * 512 + lane * 8)) = w;
    }
}

// Layer-1 input prep: X f32 row-major -> Xbf (bf16 row-major) + Xe2
__global__ __launch_bounds__(256) void conv_x_rm_kernel(
    const float* __restrict__ X, unsigned short* __restrict__ Xbf, unsigned short* __restrict__ Xe2)
{
    __shared__ __align__(16) unsigned short T[128 * 256];
    const int tid = threadIdx.x;
    const int b0 = blockIdx.x * 128;
    const float4* Xv = reinterpret_cast<const float4*>(X + (size_t)b0 * 256);
    uint2* Xo = reinterpret_cast<uint2*>(Xbf + (size_t)b0 * 256);
    #pragma unroll
    for (int it = 0; it < 32; ++it) {
        int idx4 = it * 256 + tid;
        float4 v = Xv[idx4];
        uint2 p;
        p.x = (unsigned)f2bf(v.x) | ((unsigned)f2bf(v.y) << 16);
        p.y = (unsigned)f2bf(v.z) | ((unsigned)f2bf(v.w) << 16);
        *reinterpret_cast<uint2*>(&T[idx4 * 4]) = p;
        Xo[idx4] = p;
    }
    __syncthreads();
    xe_gather3(T, Xe2, blockIdx.x, tid);
}

// Layer-2/3 input prep: Ht bf16 [256][2048] (k-major) -> Xbf row-major + Xe2
__global__ __launch_bounds__(256) void conv_x_tr_kernel(
    const unsigned short* __restrict__ Hsrc, unsigned short* __restrict__ Xbf,
    unsigned short* __restrict__ Xe2)
{
    __shared__ __align__(16) unsigned short T[128 * 256];
    const int tid = threadIdx.x;
    const int b0 = blockIdx.x * 128;
    #pragma unroll
    for (int it = 0; it < 64; ++it) {
        int lin = it * 256 + tid;
        int k = lin >> 6, bp = lin & 63;
        unsigned int v = *reinterpret_cast<const unsigned int*>(Hsrc + (size_t)k * 2048 + b0 + bp * 2);
        T[(bp * 2) * 256 + k]     = (unsigned short)(v & 0xffff);
        T[(bp * 2 + 1) * 256 + k] = (unsigned short)(v >> 16);
    }
    __syncthreads();
    uint4* Xo = reinterpret_cast<uint4*>(Xbf + (size_t)b0 * 256);
    #pragma unroll
    for (int it = 0; it < 16; ++it) {   // 4096 uint4 per 128x256 tile
        int idx8 = it * 256 + tid;
        Xo[idx8] = *reinterpret_cast<uint4*>(&T[idx8 * 8]);
    }
    xe_gather3(T, Xe2, blockIdx.x, tid);
}

// pn5: block = 4 waves, BM=64; wave wv computes the FULL triangle for n = ng*4+wv.
// One barrier total; waves independent afterwards (own shuffle-reduce, own output).
__global__ __launch_bounds__(256, 4) void pn5_kernel(
    const unsigned short* __restrict__ Xbf,  // [2048][256] bf16 row-major
    const unsigned short* __restrict__ Xe2,  // [32][8][4][64] short8 epilogue gather
    const unsigned short* __restrict__ Wt2,  // [256][256][256] bf16 symmetric triangle, j-major
    const float* __restrict__ Vt,            // [256][256] v
    const float* __restrict__ Dv,            // [256] d
    unsigned short* __restrict__ Ht)         // [256][2048] bf16
{
    __shared__ __align__(16) char Xl[32768];  // bf16 [64][256], XOR-swizzled

    const int tid  = threadIdx.x;
    const int lane = tid & 63;
    const int wv   = tid >> 6;
    const int qw   = lane >> 4;
    const int r15  = lane & 15;

    // fid -> (ng, bt): 32 bt-tiles of one n-group land on one XCD consecutively.
    const int fid = blockIdx.y * 32 + blockIdx.x;
    const int bt  = (fid >> 3) & 31;
    const int ng  = (fid & 7) + ((fid >> 8) << 3);
    const int n   = ng * 4 + wv;
    const int b0  = bt * 64;

    // ---- stage bf16 X tile (32 KB) with write-side XOR swizzle ----
    {
        const uint4* xs = reinterpret_cast<const uint4*>(Xbf + (size_t)b0 * 256);
        #pragma unroll
        for (int c = 0; c < 8; ++c) {
            int idx = c * 256 + tid;
            uint4 v = xs[idx];
            int L = idx * 16;
            int d = L ^ (((L >> 9) & 7) << 4);
            *reinterpret_cast<uint4*>(&Xl[d]) = v;
        }
    }

    const unsigned short* Wn = Wt2 + ((size_t)n << 16);
    const float* vn = Vt + n * 256;
    const float dn = Dv[n];
    const unsigned short* xe = Xe2 + (size_t)bt * 16384 + lane * 8;

    // first W frags (jt=0, kk=0) + first v pair, issued before the barrier
    short8 c0 = *reinterpret_cast<const short8*>(Wn + (size_t)r15 * 256 + qw * 8);
    short8 c1 = *reinterpret_cast<const short8*>(Wn + (size_t)(r15 + 16) * 256 + qw * 8);
    float vA = vn[r15], vB = vn[16 + r15];

    float ps[4][4];
    #pragma unroll
    for (int m = 0; m < 4; ++m)
        #pragma unroll
        for (int r = 0; r < 4; ++r) ps[m][r] = 0.f;

    __syncthreads();

    for (int jt = 0; jt < 8; ++jt) {
        const unsigned short* pA = Wn + (size_t)(jt * 32 + r15) * 256 + qw * 8;
        const unsigned short* pB = pA + 16 * 256;
        // epilogue frags for this jt (consumed at jt end — latency hidden by kk loop)
        short8 e[4];
        #pragma unroll
        for (int m = 0; m < 4; ++m)
            e[m] = *reinterpret_cast<const short8*>(xe + jt * 2048 + m * 512);
        // next jt's v pair (consumed next iteration)
        float vAn = vA, vBn = vB;
        if (jt < 7) { vAn = vn[(jt + 1) * 32 + r15]; vBn = vn[(jt + 1) * 32 + 16 + r15]; }

        f32x4 a0[4], a1[4];
        #pragma unroll
        for (int m = 0; m < 4; ++m) {
            a0[m] = f32x4{vA, vA, vA, vA};
            a1[m] = f32x4{vB, vB, vB, vB};
        }
        for (int kk = 0; kk <= jt; ++kk) {
            short8 nx0 = c0, nx1 = c1;
            if (kk < jt) {
                nx0 = *reinterpret_cast<const short8*>(pA + (kk + 1) * 32);
                nx1 = *reinterpret_cast<const short8*>(pB + (kk + 1) * 32);
            } else if (jt < 7) {
                nx0 = *reinterpret_cast<const short8*>(pA + 8192);   // next jt, kk=0
                nx1 = *reinterpret_cast<const short8*>(pB + 8192);
            }
            #pragma unroll
            for (int m = 0; m < 4; ++m) {
                const int row = m * 16 + r15;
                const int byte = (row * 512 + kk * 64 + qw * 16) ^ ((row & 7) << 4);
                short8 a = *reinterpret_cast<const short8*>(&Xl[byte]);
                a0[m] = __builtin_amdgcn_mfma_f32_16x16x32_bf16(a, c0, a0[m], 0, 0, 0);
                a1[m] = __builtin_amdgcn_mfma_f32_16x16x32_bf16(a, c1, a1[m], 0, 0, 0);
            }
            c0 = nx0; c1 = nx1;
        }
        // contraction: ps += C .* x  (j-cols of this jt)
        #pragma unroll
        for (int m = 0; m < 4; ++m)
            #pragma unroll
            for (int r = 0; r < 4; ++r)
                ps[m][r] += a0[m][r] * bf2f((unsigned short)e[m][r])
                          + a1[m][r] * bf2f((unsigned short)e[m][4 + r]);
        vA = vAn; vB = vBn;
    }

    // reduce over the 16 j-lanes (r15 bits)
    #pragma unroll
    for (int off = 1; off <= 8; off <<= 1)
        #pragma unroll
        for (int m = 0; m < 4; ++m)
            #pragma unroll
            for (int r = 0; r < 4; ++r) ps[m][r] += __shfl_xor(ps[m][r], off, 64);

    if (r15 == 0) {
        #pragma unroll
        for (int m = 0; m < 4; ++m)
            #pragma unroll
            for (int r = 0; r < 4; ++r)
                Ht[(size_t)n * 2048 + b0 + m * 16 + qw * 4 + r] = f2bf(ps[m][r] + dn);
    }
}

__global__ __launch_bounds__(256) void out_tr_kernel(
    const unsigned short* __restrict__ H3, const float* __restrict__ w_out,
    const float* __restrict__ b_out, float* __restrict__ out)
{
    __shared__ float red2[256];
    const int tid = threadIdx.x;
    const int b = blockIdx.x * 128 + (tid & 127);
    const int half = tid >> 7;
    float s = 0.f;
    #pragma unroll 8
    for (int k = 0; k < 128; ++k) {
        int nn = half * 128 + k;
        s += bf2f(H3[(size_t)nn * 2048 + b]) * w_out[nn];
    }
    red2[tid] = s;
    __syncthreads();
    if (tid < 128) out[b] = red2[tid] + red2[tid + 128] + b_out[0];
}

// ======================= FALLBACK PATH (small ws) =======================

__global__ __launch_bounds__(256, 2) void pn_layer_kernel(
    const float* __restrict__ X, const float* __restrict__ W, float* __restrict__ H)
{
    __shared__ __align__(16) char Xl[64 * 256 * 2];
    __shared__ __align__(16) char Wl[2][256 * 32 * 2];
    const int tid  = threadIdx.x;
    const int lane = tid & 63;
    const int wv   = tid >> 6;
    const int qw   = lane >> 4;
    const int r15  = lane & 15;
    const int n  = blockIdx.y;
    const int b0 = blockIdx.x * 64;
    const float* Wn = W + (size_t)n * WSTRIDE;
    {
        const float4* Xv = reinterpret_cast<const float4*>(X + (size_t)b0 * DDIM);
        #pragma unroll
        for (int it = 0; it < 16; ++it) {
            int idx4 = tid + it * 256;
            int r = idx4 >> 6, c4 = idx4 & 63;
            float4 v = Xv[r * 64 + c4];
            uint2 p;
            p.x = (unsigned)f2bf(v.x) | ((unsigned)f2bf(v.y) << 16);
            p.y = (unsigned)f2bf(v.z) | ((unsigned)f2bf(v.w) << 16);
            int byte = (r * 512 + c4 * 8) ^ ((r & 7) << 4);
            *reinterpret_cast<uint2*>(&Xl[byte]) = p;
        }
    }
    f32x4 acc[4][4];
    #pragma unroll
    for (int nf = 0; nf < 4; ++nf) {
        int j = wv * 64 + nf * 16 + r15;
        float vj = Wn[(size_t)j * WROW + 256] + Wn[65792 + j];
        #pragma unroll
        for (int m = 0; m < 4; ++m) acc[m][nf] = f32x4{vj, vj, vj, vj};
    }
    auto stageW = [&](int buf, int kk) {
        const int k0 = kk * 32;
        const int j  = tid;
        float t[32];
        #pragma unroll
        for (int k = 0; k < 32; ++k) t[k] = Wn[(size_t)(k0 + k) * WROW + j];
        char* Wb = Wl[buf];
        #pragma unroll
        for (int g = 0; g < 4; ++g) {
            unsigned int p0 = (unsigned)f2bf(t[g*8+0]) | ((unsigned)f2bf(t[g*8+1]) << 16);
            unsigned int p1 = (unsigned)f2bf(t[g*8+2]) | ((unsigned)f2bf(t[g*8+3]) << 16);
            unsigned int p2 = (unsigned)f2bf(t[g*8+4]) | ((unsigned)f2bf(t[g*8+5]) << 16);
            unsigned int p3 = (unsigned)f2bf(t[g*8+6]) | ((unsigned)f2bf(t[g*8+7]) << 16);
            int byte = (j * 64 + g * 16) ^ ((j & 7) << 4);
            *reinterpret_cast<uint4*>(&Wb[byte]) = make_uint4(p0, p1, p2, p3);
        }
    };
    auto computeK = [&](int buf, int kk) {
        char* Wb = Wl[buf];
        short8 a[4], bbf[4];
        #pragma unroll
        for (int m = 0; m < 4; ++m) {
            int row = m * 16 + r15;
            int byte = (row * 512 + kk * 64 + qw * 16) ^ ((row & 7) << 4);
            a[m] = *reinterpret_cast<short8*>(&Xl[byte]);
        }
        #pragma unroll
        for (int nf = 0; nf < 4; ++nf) {
            int j = wv * 64 + nf * 16 + r15;
            int byte = (j * 64 + qw * 16) ^ ((j & 7) << 4);
            bbf[nf] = *reinterpret_cast<short8*>(&Wb[byte]);
        }
        #pragma unroll
        for (int m = 0; m < 4; ++m)
            #pragma unroll
            for (int nf = 0; nf < 4; ++nf)
                acc[m][nf] = __builtin_amdgcn_mfma_f32_16x16x32_bf16(a[m], bbf[nf], acc[m][nf], 0, 0, 0);
    };
    stageW(0, 0);
    int cur = 0;
    #pragma unroll
    for (int kk = 0; kk < 8; ++kk) {
        __syncthreads();
        if (kk < 7) stageW(cur ^ 1, kk + 1);
        computeK(cur, kk);
        cur ^= 1;
    }
    float ps[16];
    #pragma unroll
    for (int i = 0; i < 16; ++i) ps[i] = 0.f;
    #pragma unroll
    for (int m = 0; m < 4; ++m)
        #pragma unroll
        for (int nf = 0; nf < 4; ++nf) {
            int j = wv * 64 + nf * 16 + r15;
            #pragma unroll
            for (int r = 0; r < 4; ++r) {
                int brow = m * 16 + qw * 4 + r;
                int byte = (brow * 512 + j * 2) ^ ((brow & 7) << 4);
                float xv = bf2f(*reinterpret_cast<unsigned short*>(&Xl[byte]));
                ps[m * 4 + r] += acc[m][nf][r] * xv;
            }
        }
    #pragma unroll
    for (int off = 1; off <= 8; off <<= 1)
        #pragma unroll
        for (int i = 0; i < 16; ++i) ps[i] += __shfl_xor(ps[i], off, 64);
    __syncthreads();
    float* red = reinterpret_cast<float*>(Wl);
    if (r15 == 0) {
        #pragma unroll
        for (int m = 0; m < 4; ++m)
            #pragma unroll
            for (int r = 0; r < 4; ++r)
                red[wv * 64 + m * 16 + qw * 4 + r] = ps[m * 4 + r];
    }
    __syncthreads();
    if (tid < 64) {
        float s = red[tid] + red[64 + tid] + red[128 + tid] + red[192 + tid] + Wn[66048];
        H[(size_t)(b0 + tid) * DDIM + n] = s;
    }
}

__global__ __launch_bounds__(256) void out_kernel(
    const float* __restrict__ H, const float* __restrict__ w_out,
    const float* __restrict__ b_out, float* __restrict__ out)
{
    int b = blockIdx.x * 4 + (threadIdx.x >> 6);
    int lane = threadIdx.x & 63;
    const float* h = H + (size_t)b * 256;
    float s = 0.f;
    #pragma unroll
    for (int c = 0; c < 4; ++c) s += h[lane + c * 64] * w_out[lane + c * 64];
    #pragma unroll
    for (int off = 1; off < 64; off <<= 1) s += __shfl_xor(s, off, 64);
    if (lane == 0) out[b] = s + b_out[0];
}

extern "C" void kernel_launch(void* const* d_in, const int* in_sizes, int n_in,
                              void* d_out, int out_size, void* d_ws, size_t ws_size,
                              hipStream_t stream) {
    const float* x    = (const float*)d_in[0];
    const float* W1   = (const float*)d_in[1];
    const float* W2   = (const float*)d_in[2];
    const float* W3   = (const float*)d_in[3];
    const float* wout = (const float*)d_in[4];
    const float* bout = (const float*)d_in[5];
    float* out = (float*)d_out;

    const size_t WT_BYTES  = (size_t)256 * 256 * 256 * 2;  // 33.55 MB
    const size_t XB_BYTES  = (size_t)2048 * 256 * 2;       // 1 MB
    const size_t XE2_BYTES = (size_t)32 * 16384 * 2;       // 1 MB
    const size_t VT_BYTES  = 256 * 256 * 4;                // 256 KB
    const size_t DV_BYTES  = 1024;
    const size_t HT_BYTES  = (size_t)256 * 2048 * 2;       // 1 MB (single buffer: pn never reads Ht)
    const size_t need = WT_BYTES + XB_BYTES + XE2_BYTES + VT_BYTES + DV_BYTES + HT_BYTES; // ~36.96 MB

    dim3 blk(256, 1, 1);

    if (ws_size >= need) {
        char* p = (char*)d_ws;
        unsigned short* Wt2 = (unsigned short*)p;              p += WT_BYTES;
        unsigned short* Xbf = (unsigned short*)p;              p += XB_BYTES;
        unsigned short* Xe2 = (unsigned short*)p;              p += XE2_BYTES;
        float*          Vt  = (float*)p;                       p += VT_BYTES;
        float*          Dv  = (float*)p;                       p += DV_BYTES;
        unsigned short* Ht  = (unsigned short*)p;

        const float* Ws[3] = {W1, W2, W3};

        dim3 wgrid(10, 256), lgrid(32, 64), xgrid(16);
        for (int L = 0; L < 3; ++L) {
            if (L == 0) conv_x_rm_kernel<<<xgrid, blk, 0, stream>>>(x, Xbf, Xe2);
            else        conv_x_tr_kernel<<<xgrid, blk, 0, stream>>>(Ht, Xbf, Xe2);
            conv_w2_kernel<<<wgrid, blk, 0, stream>>>(Ws[L], Wt2);
            conv_v_kernel<<<dim3(256), blk, 0, stream>>>(Ws[L], Vt, Dv);
            pn5_kernel<<<lgrid, blk, 0, stream>>>(Xbf, Xe2, Wt2, Vt, Dv, Ht);
        }
        out_tr_kernel<<<xgrid, blk, 0, stream>>>(Ht, wout, bout, out);
    } else {
        float* h1 = (float*)d_ws;
        float* h2 = h1 + 2048 * 256;
        dim3 grid(32, 256);
        pn_layer_kernel<<<grid, blk, 0, stream>>>(x,  W1, h1);
        pn_layer_kernel<<<grid, blk, 0, stream>>>(h1, W2, h2);
        pn_layer_kernel<<<grid, blk, 0, stream>>>(h2, W3, h1);
        out_kernel<<<512, blk, 0, stream>>>(h1, wout, bout, out);
    }
}

// Round 7
// 1327.590 us; speedup vs baseline: 1.5252x; 1.5252x over previous
//
#include <hip/hip_runtime.h>
#include <hip/hip_bf16.h>

typedef __attribute__((ext_vector_type(8))) short short8;   // 8 bf16 (4 VGPRs) — MFMA A/B frag
typedef __attribute__((ext_vector_type(4))) float f32x4;    // MFMA C/D frag

#define DDIM 256
#define WROW 257
#define WSTRIDE 66049  // 257*257

__device__ __forceinline__ unsigned short f2bf(float f) {
    unsigned int u = __float_as_uint(f);
    u += 0x7fff + ((u >> 16) & 1);   // RNE (finite values)
    return (unsigned short)(u >> 16);
}
__device__ __forceinline__ float bf2f(unsigned short s) {
    return __uint_as_float(((unsigned int)s) << 16);
}

// ======================= FAST PATH =======================

// Symmetrized, pre-scaled, transposed W:
//   Wt2[n][j][k] = s * (A[k][j] + A[j][k]),  s = 1 for k32<j32, 0.5 for k32==j32
__global__ __launch_bounds__(256) void conv_w2_kernel(
    const float* __restrict__ Wf, unsigned short* __restrict__ Wt2)
{
    __shared__ float tKJ[64][65];
    __shared__ float tJK[64][65];
    const int TJ[10] = {0,1,1,2,2,2,3,3,3,3};
    const int TK[10] = {0,0,1,0,1,2,0,1,2,3};
    const int tid = threadIdx.x;
    const int n   = blockIdx.y;
    const int tj  = TJ[blockIdx.x];
    const int tk  = TK[blockIdx.x];
    const float* Wn = Wf + (size_t)n * WSTRIDE;
    #pragma unroll
    for (int it = 0; it < 16; ++it) {
        int r = it * 4 + (tid >> 6);
        int c = tid & 63;
        tKJ[r][c] = Wn[(size_t)(tk * 64 + r) * WROW + tj * 64 + c];
        tJK[r][c] = Wn[(size_t)(tj * 64 + r) * WROW + tk * 64 + c];
    }
    __syncthreads();
    unsigned short* out = Wt2 + ((size_t)n << 16);
    #pragma unroll
    for (int it = 0; it < 8; ++it) {
        int jl = it * 8 + (tid >> 5);
        int k2 = (tid & 31) * 2;
        int p32 = tk * 2 + (k2 >> 5);
        int q32 = tj * 2 + (jl >> 5);
        if (p32 <= q32) {
            float sc = (p32 == q32) ? 0.5f : 1.0f;
            float v0 = sc * (tKJ[k2][jl]     + tJK[jl][k2]);
            float v1 = sc * (tKJ[k2 + 1][jl] + tJK[jl][k2 + 1]);
            unsigned int u = (unsigned)f2bf(v0) | ((unsigned)f2bf(v1) << 16);
            *reinterpret_cast<unsigned int*>(out + (size_t)(tj * 64 + jl) * 256 + tk * 64 + k2) = u;
        }
    }
}

// Vt[n][j] = W[n][j][256] + W[n][256][j];  Dv[n] = W[n][256][256]
__global__ void conv_v_kernel(const float* __restrict__ Wf,
                              float* __restrict__ Vt, float* __restrict__ Dv)
{
    int n = blockIdx.x, j = threadIdx.x;
    const float* Wn = Wf + (size_t)n * WSTRIDE;
    Vt[n * 256 + j] = Wn[(size_t)j * WROW + 256] + Wn[65792 + j];
    if (j == 0) Dv[n] = Wn[66048];
}

// Epilogue gather: Xe2[bt][jt][m][lane] = short8 { x[row(m,qw,r)][jA] r=0..3, x[row][jB] r=0..3 }
//   jA = jt*32 + r15, jB = jA+16, row = m*16 + qw*4 + r (bt-local).  Lane-only-dependent.
__device__ __forceinline__ void xe_gather3(const unsigned short* T, unsigned short* Xe2,
                                           int bx, int tid) {
    const int lane = tid & 63, g = tid >> 6, qw = (tid >> 4) & 3, r15 = tid & 15;
    #pragma unroll
    for (int it = 0; it < 16; ++it) {
        int c  = g * 16 + it;        // flat (h, jt, m) in [0,64)
        int h  = c >> 5;
        int jt = (c >> 2) & 7;
        int m  = c & 3;
        int rbase = h * 64 + m * 16 + qw * 4;
        int jA = jt * 32 + r15;
        unsigned int u0 = T[(rbase + 0) * 256 + jA];
        unsigned int u1 = T[(rbase + 1) * 256 + jA];
        unsigned int u2 = T[(rbase + 2) * 256 + jA];
        unsigned int u3 = T[(rbase + 3) * 256 + jA];
        unsigned int v0 = T[(rbase + 0) * 256 + jA + 16];
        unsigned int v1 = T[(rbase + 1) * 256 + jA + 16];
        unsigned int v2 = T[(rbase + 2) * 256 + jA + 16];
        unsigned int v3 = T[(rbase + 3) * 256 + jA + 16];
        uint4 w = make_uint4(u0 | (u1 << 16), u2 | (u3 << 16),
                             v0 | (v1 << 16), v2 | (v3 << 16));
        *reinterpret_cast<uint4*>(Xe2 + ((size_t)(bx * 2 + h) * 16384 + jt * 2048 + m * 512 + lane * 8)) = w;
    }
}

// Layer-1 input prep: X f32 row-major -> Xbf (bf16 row-major) + Xe2
__global__ __launch_bounds__(256) void conv_x_rm_kernel(
    const float* __restrict__ X, unsigned short* __restrict__ Xbf, unsigned short* __restrict__ Xe2)
{
    __shared__ __align__(16) unsigned short T[128 * 256];
    const int tid = threadIdx.x;
    const int b0 = blockIdx.x * 128;
    const float4* Xv = reinterpret_cast<const float4*>(X + (size_t)b0 * 256);
    uint2* Xo = reinterpret_cast<uint2*>(Xbf + (size_t)b0 * 256);
    #pragma unroll
    for (int it = 0; it < 32; ++it) {
        int idx4 = it * 256 + tid;
        float4 v = Xv[idx4];
        uint2 p;
        p.x = (unsigned)f2bf(v.x) | ((unsigned)f2bf(v.y) << 16);
        p.y = (unsigned)f2bf(v.z) | ((unsigned)f2bf(v.w) << 16);
        *reinterpret_cast<uint2*>(&T[idx4 * 4]) = p;
        Xo[idx4] = p;
    }
    __syncthreads();
    xe_gather3(T, Xe2, blockIdx.x, tid);
}

// Layer-2/3 input prep: Ht bf16 [256][2048] (k-major) -> Xbf row-major + Xe2
__global__ __launch_bounds__(256) void conv_x_tr_kernel(
    const unsigned short* __restrict__ Hsrc, unsigned short* __restrict__ Xbf,
    unsigned short* __restrict__ Xe2)
{
    __shared__ __align__(16) unsigned short T[128 * 256];
    const int tid = threadIdx.x;
    const int b0 = blockIdx.x * 128;
    #pragma unroll
    for (int it = 0; it < 64; ++it) {
        int lin = it * 256 + tid;
        int k = lin >> 6, bp = lin & 63;
        unsigned int v = *reinterpret_cast<const unsigned int*>(Hsrc + (size_t)k * 2048 + b0 + bp * 2);
        T[(bp * 2) * 256 + k]     = (unsigned short)(v & 0xffff);
        T[(bp * 2 + 1) * 256 + k] = (unsigned short)(v >> 16);
    }
    __syncthreads();
    uint4* Xo = reinterpret_cast<uint4*>(Xbf + (size_t)b0 * 256);
    #pragma unroll
    for (int it = 0; it < 16; ++it) {   // 4096 uint4 per 128x256 tile
        int idx8 = it * 256 + tid;
        Xo[idx8] = *reinterpret_cast<uint4*>(&T[idx8 * 8]);
    }
    xe_gather3(T, Xe2, blockIdx.x, tid);
}

// pn5: block = 4 waves, BM=64; wave wv computes the FULL triangle for n = ng*4+wv.
// One barrier total; waves independent afterwards.
// launch_bounds min-waves=3 (NOT 4): cap 512/3=168 regs/wave. Live state ~130
// (32 acc + 16 ps + 16 e + 16 W-prefetch + addr/staging); at min-waves=4 the
// 128-reg cap forced a ~40-reg spill -> 2.25 GB/dispatch scratch traffic (R6).
__global__ __launch_bounds__(256, 3) void pn5_kernel(
    const unsigned short* __restrict__ Xbf,  // [2048][256] bf16 row-major
    const unsigned short* __restrict__ Xe2,  // [32][8][4][64] short8 epilogue gather
    const unsigned short* __restrict__ Wt2,  // [256][256][256] bf16 symmetric triangle, j-major
    const float* __restrict__ Vt,            // [256][256] v
    const float* __restrict__ Dv,            // [256] d
    unsigned short* __restrict__ Ht)         // [256][2048] bf16
{
    __shared__ __align__(16) char Xl[32768];  // bf16 [64][256], XOR-swizzled

    const int tid  = threadIdx.x;
    const int lane = tid & 63;
    const int wv   = tid >> 6;
    const int qw   = lane >> 4;
    const int r15  = lane & 15;

    // fid -> (ng, bt): 32 bt-tiles of one n-group land on one XCD consecutively.
    const int fid = blockIdx.y * 32 + blockIdx.x;
    const int bt  = (fid >> 3) & 31;
    const int ng  = (fid & 7) + ((fid >> 8) << 3);
    const int n   = ng * 4 + wv;
    const int b0  = bt * 64;

    // ---- stage bf16 X tile (32 KB) with write-side XOR swizzle ----
    {
        const uint4* xs = reinterpret_cast<const uint4*>(Xbf + (size_t)b0 * 256);
        #pragma unroll
        for (int c = 0; c < 8; ++c) {
            int idx = c * 256 + tid;
            uint4 v = xs[idx];
            int L = idx * 16;
            int d = L ^ (((L >> 9) & 7) << 4);
            *reinterpret_cast<uint4*>(&Xl[d]) = v;
        }
    }

    const unsigned short* Wn = Wt2 + ((size_t)n << 16);
    const float* vn = Vt + n * 256;
    const float dn = Dv[n];
    const unsigned short* xe = Xe2 + (size_t)bt * 16384 + lane * 8;

    // first W frags (jt=0, kk=0) + first v pair, issued before the barrier
    short8 c0 = *reinterpret_cast<const short8*>(Wn + (size_t)r15 * 256 + qw * 8);
    short8 c1 = *reinterpret_cast<const short8*>(Wn + (size_t)(r15 + 16) * 256 + qw * 8);
    float vA = vn[r15], vB = vn[16 + r15];

    float ps[4][4];
    #pragma unroll
    for (int m = 0; m < 4; ++m)
        #pragma unroll
        for (int r = 0; r < 4; ++r) ps[m][r] = 0.f;

    __syncthreads();

    for (int jt = 0; jt < 8; ++jt) {
        const unsigned short* pA = Wn + (size_t)(jt * 32 + r15) * 256 + qw * 8;
        const unsigned short* pB = pA + 16 * 256;
        // epilogue frags for this jt (consumed at jt end — latency hidden by kk loop)
        short8 e[4];
        #pragma unroll
        for (int m = 0; m < 4; ++m)
            e[m] = *reinterpret_cast<const short8*>(xe + jt * 2048 + m * 512);
        // next jt's v pair (consumed next iteration)
        float vAn = vA, vBn = vB;
        if (jt < 7) { vAn = vn[(jt + 1) * 32 + r15]; vBn = vn[(jt + 1) * 32 + 16 + r15]; }

        f32x4 a0[4], a1[4];
        #pragma unroll
        for (int m = 0; m < 4; ++m) {
            a0[m] = f32x4{vA, vA, vA, vA};
            a1[m] = f32x4{vB, vB, vB, vB};
        }
        for (int kk = 0; kk <= jt; ++kk) {
            short8 nx0 = c0, nx1 = c1;
            if (kk < jt) {
                nx0 = *reinterpret_cast<const short8*>(pA + (kk + 1) * 32);
                nx1 = *reinterpret_cast<const short8*>(pB + (kk + 1) * 32);
            } else if (jt < 7) {
                nx0 = *reinterpret_cast<const short8*>(pA + 8192);   // next jt, kk=0
                nx1 = *reinterpret_cast<const short8*>(pB + 8192);
            }
            #pragma unroll
            for (int m = 0; m < 4; ++m) {
                const int row = m * 16 + r15;
                const int byte = (row * 512 + kk * 64 + qw * 16) ^ ((row & 7) << 4);
                short8 a = *reinterpret_cast<const short8*>(&Xl[byte]);
                a0[m] = __builtin_amdgcn_mfma_f32_16x16x32_bf16(a, c0, a0[m], 0, 0, 0);
                a1[m] = __builtin_amdgcn_mfma_f32_16x16x32_bf16(a, c1, a1[m], 0, 0, 0);
            }
            c0 = nx0; c1 = nx1;
        }
        // contraction: ps += C .* x  (j-cols of this jt)
        #pragma unroll
        for (int m = 0; m < 4; ++m)
            #pragma unroll
            for (int r = 0; r < 4; ++r)
                ps[m][r] += a0[m][r] * bf2f((unsigned short)e[m][r])
                          + a1[m][r] * bf2f((unsigned short)e[m][4 + r]);
        vA = vAn; vB = vBn;
    }

    // reduce over the 16 j-lanes (r15 bits)
    #pragma unroll
    for (int off = 1; off <= 8; off <<= 1)
        #pragma unroll
        for (int m = 0; m < 4; ++m)
            #pragma unroll
            for (int r = 0; r < 4; ++r) ps[m][r] += __shfl_xor(ps[m][r], off, 64);

    if (r15 == 0) {
        #pragma unroll
        for (int m = 0; m < 4; ++m)
            #pragma unroll
            for (int r = 0; r < 4; ++r)
                Ht[(size_t)n * 2048 + b0 + m * 16 + qw * 4 + r] = f2bf(ps[m][r] + dn);
    }
}

__global__ __launch_bounds__(256) void out_tr_kernel(
    const unsigned short* __restrict__ H3, const float* __restrict__ w_out,
    const float* __restrict__ b_out, float* __restrict__ out)
{
    __shared__ float red2[256];
    const int tid = threadIdx.x;
    const int b = blockIdx.x * 128 + (tid & 127);
    const int half = tid >> 7;
    float s = 0.f;
    #pragma unroll 8
    for (int k = 0; k < 128; ++k) {
        int nn = half * 128 + k;
        s += bf2f(H3[(size_t)nn * 2048 + b]) * w_out[nn];
    }
    red2[tid] = s;
    __syncthreads();
    if (tid < 128) out[b] = red2[tid] + red2[tid + 128] + b_out[0];
}

// ======================= FALLBACK PATH (small ws) =======================

__global__ __launch_bounds__(256, 2) void pn_layer_kernel(
    const float* __restrict__ X, const float* __restrict__ W, float* __restrict__ H)
{
    __shared__ __align__(16) char Xl[64 * 256 * 2];
    __shared__ __align__(16) char Wl[2][256 * 32 * 2];
    const int tid  = threadIdx.x;
    const int lane = tid & 63;
    const int wv   = tid >> 6;
    const int qw   = lane >> 4;
    const int r15  = lane & 15;
    const int n  = blockIdx.y;
    const int b0 = blockIdx.x * 64;
    const float* Wn = W + (size_t)n * WSTRIDE;
    {
        const float4* Xv = reinterpret_cast<const float4*>(X + (size_t)b0 * DDIM);
        #pragma unroll
        for (int it = 0; it < 16; ++it) {
            int idx4 = tid + it * 256;
            int r = idx4 >> 6, c4 = idx4 & 63;
            float4 v = Xv[r * 64 + c4];
            uint2 p;
            p.x = (unsigned)f2bf(v.x) | ((unsigned)f2bf(v.y) << 16);
            p.y = (unsigned)f2bf(v.z) | ((unsigned)f2bf(v.w) << 16);
            int byte = (r * 512 + c4 * 8) ^ ((r & 7) << 4);
            *reinterpret_cast<uint2*>(&Xl[byte]) = p;
        }
    }
    f32x4 acc[4][4];
    #pragma unroll
    for (int nf = 0; nf < 4; ++nf) {
        int j = wv * 64 + nf * 16 + r15;
        float vj = Wn[(size_t)j * WROW + 256] + Wn[65792 + j];
        #pragma unroll
        for (int m = 0; m < 4; ++m) acc[m][nf] = f32x4{vj, vj, vj, vj};
    }
    auto stageW = [&](int buf, int kk) {
        const int k0 = kk * 32;
        const int j  = tid;
        float t[32];
        #pragma unroll
        for (int k = 0; k < 32; ++k) t[k] = Wn[(size_t)(k0 + k) * WROW + j];
        char* Wb = Wl[buf];
        #pragma unroll
        for (int g = 0; g < 4; ++g) {
            unsigned int p0 = (unsigned)f2bf(t[g*8+0]) | ((unsigned)f2bf(t[g*8+1]) << 16);
            unsigned int p1 = (unsigned)f2bf(t[g*8+2]) | ((unsigned)f2bf(t[g*8+3]) << 16);
            unsigned int p2 = (unsigned)f2bf(t[g*8+4]) | ((unsigned)f2bf(t[g*8+5]) << 16);
            unsigned int p3 = (unsigned)f2bf(t[g*8+6]) | ((unsigned)f2bf(t[g*8+7]) << 16);
            int byte = (j * 64 + g * 16) ^ ((j & 7) << 4);
            *reinterpret_cast<uint4*>(&Wb[byte]) = make_uint4(p0, p1, p2, p3);
        }
    };
    auto computeK = [&](int buf, int kk) {
        char* Wb = Wl[buf];
        short8 a[4], bbf[4];
        #pragma unroll
        for (int m = 0; m < 4; ++m) {
            int row = m * 16 + r15;
            int byte = (row * 512 + kk * 64 + qw * 16) ^ ((row & 7) << 4);
            a[m] = *reinterpret_cast<short8*>(&Xl[byte]);
        }
        #pragma unroll
        for (int nf = 0; nf < 4; ++nf) {
            int j = wv * 64 + nf * 16 + r15;
            int byte = (j * 64 + qw * 16) ^ ((j & 7) << 4);
            bbf[nf] = *reinterpret_cast<short8*>(&Wb[byte]);
        }
        #pragma unroll
        for (int m = 0; m < 4; ++m)
            #pragma unroll
            for (int nf = 0; nf < 4; ++nf)
                acc[m][nf] = __builtin_amdgcn_mfma_f32_16x16x32_bf16(a[m], bbf[nf], acc[m][nf], 0, 0, 0);
    };
    stageW(0, 0);
    int cur = 0;
    #pragma unroll
    for (int kk = 0; kk < 8; ++kk) {
        __syncthreads();
        if (kk < 7) stageW(cur ^ 1, kk + 1);
        computeK(cur, kk);
        cur ^= 1;
    }
    float ps[16];
    #pragma unroll
    for (int i = 0; i < 16; ++i) ps[i] = 0.f;
    #pragma unroll
    for (int m = 0; m < 4; ++m)
        #pragma unroll
        for (int nf = 0; nf < 4; ++nf) {
            int j = wv * 64 + nf * 16 + r15;
            #pragma unroll
            for (int r = 0; r < 4; ++r) {
                int brow = m * 16 + qw * 4 + r;
                int byte = (brow * 512 + j * 2) ^ ((brow & 7) << 4);
                float xv = bf2f(*reinterpret_cast<unsigned short*>(&Xl[byte]));
                ps[m * 4 + r] += acc[m][nf][r] * xv;
            }
        }
    #pragma unroll
    for (int off = 1; off <= 8; off <<= 1)
        #pragma unroll
        for (int i = 0; i < 16; ++i) ps[i] += __shfl_xor(ps[i], off, 64);
    __syncthreads();
    float* red = reinterpret_cast<float*>(Wl);
    if (r15 == 0) {
        #pragma unroll
        for (int m = 0; m < 4; ++m)
            #pragma unroll
            for (int r = 0; r < 4; ++r)
                red[wv * 64 + m * 16 + qw * 4 + r] = ps[m * 4 + r];
    }
    __syncthreads();
    if (tid < 64) {
        float s = red[tid] + red[64 + tid] + red[128 + tid] + red[192 + tid] + Wn[66048];
        H[(size_t)(b0 + tid) * DDIM + n] = s;
    }
}

__global__ __launch_bounds__(256) void out_kernel(
    const float* __restrict__ H, const float* __restrict__ w_out,
    const float* __restrict__ b_out, float* __restrict__ out)
{
    int b = blockIdx.x * 4 + (threadIdx.x >> 6);
    int lane = threadIdx.x & 63;
    const float* h = H + (size_t)b * 256;
    float s = 0.f;
    #pragma unroll
    for (int c = 0; c < 4; ++c) s += h[lane + c * 64] * w_out[lane + c * 64];
    #pragma unroll
    for (int off = 1; off < 64; off <<= 1) s += __shfl_xor(s, off, 64);
    if (lane == 0) out[b] = s + b_out[0];
}

extern "C" void kernel_launch(void* const* d_in, const int* in_sizes, int n_in,
                              void* d_out, int out_size, void* d_ws, size_t ws_size,
                              hipStream_t stream) {
    const float* x    = (const float*)d_in[0];
    const float* W1   = (const float*)d_in[1];
    const float* W2   = (const float*)d_in[2];
    const float* W3   = (const float*)d_in[3];
    const float* wout = (const float*)d_in[4];
    const float* bout = (const float*)d_in[5];
    float* out = (float*)d_out;

    const size_t WT_BYTES  = (size_t)256 * 256 * 256 * 2;  // 33.55 MB
    const size_t XB_BYTES  = (size_t)2048 * 256 * 2;       // 1 MB
    const size_t XE2_BYTES = (size_t)32 * 16384 * 2;       // 1 MB
    const size_t VT_BYTES  = 256 * 256 * 4;                // 256 KB
    const size_t DV_BYTES  = 1024;
    const size_t HT_BYTES  = (size_t)256 * 2048 * 2;       // 1 MB (single buffer: pn never reads Ht)
    const size_t need = WT_BYTES + XB_BYTES + XE2_BYTES + VT_BYTES + DV_BYTES + HT_BYTES; // ~36.96 MB

    dim3 blk(256, 1, 1);

    if (ws_size >= need) {
        char* p = (char*)d_ws;
        unsigned short* Wt2 = (unsigned short*)p;              p += WT_BYTES;
        unsigned short* Xbf = (unsigned short*)p;              p += XB_BYTES;
        unsigned short* Xe2 = (unsigned short*)p;              p += XE2_BYTES;
        float*          Vt  = (float*)p;                       p += VT_BYTES;
        float*          Dv  = (float*)p;                       p += DV_BYTES;
        unsigned short* Ht  = (unsigned short*)p;

        const float* Ws[3] = {W1, W2, W3};

        dim3 wgrid(10, 256), lgrid(32, 64), xgrid(16);
        for (int L = 0; L < 3; ++L) {
            if (L == 0) conv_x_rm_kernel<<<xgrid, blk, 0, stream>>>(x, Xbf, Xe2);
            else        conv_x_tr_kernel<<<xgrid, blk, 0, stream>>>(Ht, Xbf, Xe2);
            conv_w2_kernel<<<wgrid, blk, 0, stream>>>(Ws[L], Wt2);
            conv_v_kernel<<<dim3(256), blk, 0, stream>>>(Ws[L], Vt, Dv);
            pn5_kernel<<<lgrid, blk, 0, stream>>>(Xbf, Xe2, Wt2, Vt, Dv, Ht);
        }
        out_tr_kernel<<<xgrid, blk, 0, stream>>>(Ht, wout, bout, out);
    } else {
        float* h1 = (float*)d_ws;
        float* h2 = h1 + 2048 * 256;
        dim3 grid(32, 256);
        pn_layer_kernel<<<grid, blk, 0, stream>>>(x,  W1, h1);
        pn_layer_kernel<<<grid, blk, 0, stream>>>(h1, W2, h2);
        pn_layer_kernel<<<grid, blk, 0, stream>>>(h2, W3, h1);
        out_kernel<<<512, blk, 0, stream>>>(h1, wout, bout, out);
    }
}

// Round 8
// 1276.901 us; speedup vs baseline: 1.5857x; 1.0397x over previous
//
#include <hip/hip_runtime.h>
#include <hip/hip_bf16.h>

typedef __attribute__((ext_vector_type(8))) short short8;   // 8 bf16 (4 VGPRs) — MFMA A/B frag
typedef __attribute__((ext_vector_type(4))) float f32x4;    // MFMA C/D frag

#define DDIM 256
#define WROW 257
#define WSTRIDE 66049  // 257*257

__device__ __forceinline__ unsigned short f2bf(float f) {
    unsigned int u = __float_as_uint(f);
    u += 0x7fff + ((u >> 16) & 1);   // RNE (finite values)
    return (unsigned short)(u >> 16);
}
__device__ __forceinline__ float bf2f(unsigned short s) {
    return __uint_as_float(((unsigned int)s) << 16);
}

// ======================= FAST PATH =======================

// Symmetrized, pre-scaled, transposed W:
//   Wt2[n][j][k] = s * (A[k][j] + A[j][k]),  s = 1 for k32<j32, 0.5 for k32==j32
__global__ __launch_bounds__(256) void conv_w2_kernel(
    const float* __restrict__ Wf, unsigned short* __restrict__ Wt2)
{
    __shared__ float tKJ[64][65];
    __shared__ float tJK[64][65];
    const int TJ[10] = {0,1,1,2,2,2,3,3,3,3};
    const int TK[10] = {0,0,1,0,1,2,0,1,2,3};
    const int tid = threadIdx.x;
    const int n   = blockIdx.y;
    const int tj  = TJ[blockIdx.x];
    const int tk  = TK[blockIdx.x];
    const float* Wn = Wf + (size_t)n * WSTRIDE;
    #pragma unroll
    for (int it = 0; it < 16; ++it) {
        int r = it * 4 + (tid >> 6);
        int c = tid & 63;
        tKJ[r][c] = Wn[(size_t)(tk * 64 + r) * WROW + tj * 64 + c];
        tJK[r][c] = Wn[(size_t)(tj * 64 + r) * WROW + tk * 64 + c];
    }
    __syncthreads();
    unsigned short* out = Wt2 + ((size_t)n << 16);
    #pragma unroll
    for (int it = 0; it < 8; ++it) {
        int jl = it * 8 + (tid >> 5);
        int k2 = (tid & 31) * 2;
        int p32 = tk * 2 + (k2 >> 5);
        int q32 = tj * 2 + (jl >> 5);
        if (p32 <= q32) {
            float sc = (p32 == q32) ? 0.5f : 1.0f;
            float v0 = sc * (tKJ[k2][jl]     + tJK[jl][k2]);
            float v1 = sc * (tKJ[k2 + 1][jl] + tJK[jl][k2 + 1]);
            unsigned int u = (unsigned)f2bf(v0) | ((unsigned)f2bf(v1) << 16);
            *reinterpret_cast<unsigned int*>(out + (size_t)(tj * 64 + jl) * 256 + tk * 64 + k2) = u;
        }
    }
}

// Vt[n][j] = W[n][j][256] + W[n][256][j];  Dv[n] = W[n][256][256]
__global__ void conv_v_kernel(const float* __restrict__ Wf,
                              float* __restrict__ Vt, float* __restrict__ Dv)
{
    int n = blockIdx.x, j = threadIdx.x;
    const float* Wn = Wf + (size_t)n * WSTRIDE;
    Vt[n * 256 + j] = Wn[(size_t)j * WROW + 256] + Wn[65792 + j];
    if (j == 0) Dv[n] = Wn[66048];
}

// Epilogue gather: Xe2[bt][jt][m][lane] = short8 { x[row(m,qw,r)][jA] r=0..3, x[row][jB] r=0..3 }
//   jA = jt*32 + r15, jB = jA+16, row = m*16 + qw*4 + r (bt-local).  Lane-only-dependent.
__device__ __forceinline__ void xe_gather3(const unsigned short* T, unsigned short* Xe2,
                                           int bx, int tid) {
    const int lane = tid & 63, g = tid >> 6, qw = (tid >> 4) & 3, r15 = tid & 15;
    #pragma unroll
    for (int it = 0; it < 16; ++it) {
        int c  = g * 16 + it;        // flat (h, jt, m) in [0,64)
        int h  = c >> 5;
        int jt = (c >> 2) & 7;
        int m  = c & 3;
        int rbase = h * 64 + m * 16 + qw * 4;
        int jA = jt * 32 + r15;
        unsigned int u0 = T[(rbase + 0) * 256 + jA];
        unsigned int u1 = T[(rbase + 1) * 256 + jA];
        unsigned int u2 = T[(rbase + 2) * 256 + jA];
        unsigned int u3 = T[(rbase + 3) * 256 + jA];
        unsigned int v0 = T[(rbase + 0) * 256 + jA + 16];
        unsigned int v1 = T[(rbase + 1) * 256 + jA + 16];
        unsigned int v2 = T[(rbase + 2) * 256 + jA + 16];
        unsigned int v3 = T[(rbase + 3) * 256 + jA + 16];
        uint4 w = make_uint4(u0 | (u1 << 16), u2 | (u3 << 16),
                             v0 | (v1 << 16), v2 | (v3 << 16));
        *reinterpret_cast<uint4*>(Xe2 + ((size_t)(bx * 2 + h) * 16384 + jt * 2048 + m * 512 + lane * 8)) = w;
    }
}

// Layer-1 input prep: X f32 row-major -> Xbf (bf16 row-major) + Xe2
__global__ __launch_bounds__(256) void conv_x_rm_kernel(
    const float* __restrict__ X, unsigned short* __restrict__ Xbf, unsigned short* __restrict__ Xe2)
{
    __shared__ __align__(16) unsigned short T[128 * 256];
    const int tid = threadIdx.x;
    const int b0 = blockIdx.x * 128;
    const float4* Xv = reinterpret_cast<const float4*>(X + (size_t)b0 * 256);
    uint2* Xo = reinterpret_cast<uint2*>(Xbf + (size_t)b0 * 256);
    #pragma unroll
    for (int it = 0; it < 32; ++it) {
        int idx4 = it * 256 + tid;
        float4 v = Xv[idx4];
        uint2 p;
        p.x = (unsigned)f2bf(v.x) | ((unsigned)f2bf(v.y) << 16);
        p.y = (unsigned)f2bf(v.z) | ((unsigned)f2bf(v.w) << 16);
        *reinterpret_cast<uint2*>(&T[idx4 * 4]) = p;
        Xo[idx4] = p;
    }
    __syncthreads();
    xe_gather3(T, Xe2, blockIdx.x, tid);
}

// Layer-2/3 input prep: Ht bf16 [256][2048] (k-major) -> Xbf row-major + Xe2
__global__ __launch_bounds__(256) void conv_x_tr_kernel(
    const unsigned short* __restrict__ Hsrc, unsigned short* __restrict__ Xbf,
    unsigned short* __restrict__ Xe2)
{
    __shared__ __align__(16) unsigned short T[128 * 256];
    const int tid = threadIdx.x;
    const int b0 = blockIdx.x * 128;
    #pragma unroll
    for (int it = 0; it < 64; ++it) {
        int lin = it * 256 + tid;
        int k = lin >> 6, bp = lin & 63;
        unsigned int v = *reinterpret_cast<const unsigned int*>(Hsrc + (size_t)k * 2048 + b0 + bp * 2);
        T[(bp * 2) * 256 + k]     = (unsigned short)(v & 0xffff);
        T[(bp * 2 + 1) * 256 + k] = (unsigned short)(v >> 16);
    }
    __syncthreads();
    uint4* Xo = reinterpret_cast<uint4*>(Xbf + (size_t)b0 * 256);
    #pragma unroll
    for (int it = 0; it < 16; ++it) {   // 4096 uint4 per 128x256 tile
        int idx8 = it * 256 + tid;
        Xo[idx8] = *reinterpret_cast<uint4*>(&T[idx8 * 8]);
    }
    xe_gather3(T, Xe2, blockIdx.x, tid);
}

// pn6: block = 4 waves, BM=64; wave wv computes the FULL triangle for n = ng*4+wv.
// One barrier total; waves independent afterwards. Register-dieted vs pn5 (R7 spilled):
// no e-prefetch, no v-prefetch, no cross-jt W prefetch -> kk-loop live set
// ~= 32 acc + 16 ps + 16 c/nx + pointers ~= 120 < 168 cap @ min-waves=3.
__global__ __launch_bounds__(256, 3) void pn6_kernel(
    const unsigned short* __restrict__ Xbf,  // [2048][256] bf16 row-major
    const unsigned short* __restrict__ Xe2,  // [32][8][4][64] short8 epilogue gather
    const unsigned short* __restrict__ Wt2,  // [256][256][256] bf16 symmetric triangle, j-major
    const float* __restrict__ Vt,            // [256][256] v
    const float* __restrict__ Dv,            // [256] d
    unsigned short* __restrict__ Ht)         // [256][2048] bf16
{
    __shared__ __align__(16) char Xl[32768];  // bf16 [64][256], XOR-swizzled

    const int tid  = threadIdx.x;
    const int lane = tid & 63;
    const int wv   = tid >> 6;
    const int qw   = lane >> 4;
    const int r15  = lane & 15;

    // fid -> (ng, bt): 32 bt-tiles of one n-group land on one XCD consecutively.
    const int fid = blockIdx.y * 32 + blockIdx.x;
    const int bt  = (fid >> 3) & 31;
    const int ng  = (fid & 7) + ((fid >> 8) << 3);
    const int n   = ng * 4 + wv;
    const int b0  = bt * 64;

    // ---- stage bf16 X tile (32 KB) with write-side XOR swizzle ----
    {
        const uint4* xs = reinterpret_cast<const uint4*>(Xbf + (size_t)b0 * 256);
        #pragma unroll
        for (int c = 0; c < 8; ++c) {
            int idx = c * 256 + tid;
            uint4 v = xs[idx];
            int L = idx * 16;
            int d = L ^ (((L >> 9) & 7) << 4);
            *reinterpret_cast<uint4*>(&Xl[d]) = v;
        }
    }

    const unsigned short* Wn = Wt2 + ((size_t)n << 16);
    const float* vn = Vt + n * 256;
    const unsigned short* xe = Xe2 + (size_t)bt * 16384 + lane * 8;

    float ps[4][4];
    #pragma unroll
    for (int m = 0; m < 4; ++m)
        #pragma unroll
        for (int r = 0; r < 4; ++r) ps[m][r] = 0.f;

    __syncthreads();

    for (int jt = 0; jt < 8; ++jt) {
        const unsigned short* pA = Wn + (size_t)(jt * 32 + r15) * 256 + qw * 8;
        const unsigned short* pB = pA + 16 * 256;
        const float vA = vn[jt * 32 + r15];
        const float vB = vn[jt * 32 + 16 + r15];
        short8 c0 = *reinterpret_cast<const short8*>(pA);
        short8 c1 = *reinterpret_cast<const short8*>(pB);

        f32x4 a0[4], a1[4];
        #pragma unroll
        for (int m = 0; m < 4; ++m) {
            a0[m] = f32x4{vA, vA, vA, vA};
            a1[m] = f32x4{vB, vB, vB, vB};
        }
        for (int kk = 0; kk <= jt; ++kk) {
            short8 nx0, nx1;
            const bool more = kk < jt;
            if (more) {
                nx0 = *reinterpret_cast<const short8*>(pA + (kk + 1) * 32);
                nx1 = *reinterpret_cast<const short8*>(pB + (kk + 1) * 32);
            }
            #pragma unroll
            for (int m = 0; m < 4; ++m) {
                const int row = m * 16 + r15;
                const int byte = (row * 512 + kk * 64 + qw * 16) ^ ((row & 7) << 4);
                short8 a = *reinterpret_cast<const short8*>(&Xl[byte]);
                a0[m] = __builtin_amdgcn_mfma_f32_16x16x32_bf16(a, c0, a0[m], 0, 0, 0);
                a1[m] = __builtin_amdgcn_mfma_f32_16x16x32_bf16(a, c1, a1[m], 0, 0, 0);
            }
            if (more) { c0 = nx0; c1 = nx1; }
        }
        // contraction: ps += C .* x  (j-cols of this jt), e loaded directly (L2-hot)
        #pragma unroll
        for (int m = 0; m < 4; ++m) {
            short8 e = *reinterpret_cast<const short8*>(xe + jt * 2048 + m * 512);
            #pragma unroll
            for (int r = 0; r < 4; ++r)
                ps[m][r] += a0[m][r] * bf2f((unsigned short)e[r])
                          + a1[m][r] * bf2f((unsigned short)e[4 + r]);
        }
    }

    // reduce over the 16 j-lanes (r15 bits)
    #pragma unroll
    for (int off = 1; off <= 8; off <<= 1)
        #pragma unroll
        for (int m = 0; m < 4; ++m)
            #pragma unroll
            for (int r = 0; r < 4; ++r) ps[m][r] += __shfl_xor(ps[m][r], off, 64);

    if (r15 == 0) {
        const float dn = Dv[n];
        #pragma unroll
        for (int m = 0; m < 4; ++m)
            #pragma unroll
            for (int r = 0; r < 4; ++r)
                Ht[(size_t)n * 2048 + b0 + m * 16 + qw * 4 + r] = f2bf(ps[m][r] + dn);
    }
}

__global__ __launch_bounds__(256) void out_tr_kernel(
    const unsigned short* __restrict__ H3, const float* __restrict__ w_out,
    const float* __restrict__ b_out, float* __restrict__ out)
{
    __shared__ float red2[256];
    const int tid = threadIdx.x;
    const int b = blockIdx.x * 128 + (tid & 127);
    const int half = tid >> 7;
    float s = 0.f;
    #pragma unroll 8
    for (int k = 0; k < 128; ++k) {
        int nn = half * 128 + k;
        s += bf2f(H3[(size_t)nn * 2048 + b]) * w_out[nn];
    }
    red2[tid] = s;
    __syncthreads();
    if (tid < 128) out[b] = red2[tid] + red2[tid + 128] + b_out[0];
}

// ======================= FALLBACK PATH (small ws) =======================

__global__ __launch_bounds__(256, 2) void pn_layer_kernel(
    const float* __restrict__ X, const float* __restrict__ W, float* __restrict__ H)
{
    __shared__ __align__(16) char Xl[64 * 256 * 2];
    __shared__ __align__(16) char Wl[2][256 * 32 * 2];
    const int tid  = threadIdx.x;
    const int lane = tid & 63;
    const int wv   = tid >> 6;
    const int qw   = lane >> 4;
    const int r15  = lane & 15;
    const int n  = blockIdx.y;
    const int b0 = blockIdx.x * 64;
    const float* Wn = W + (size_t)n * WSTRIDE;
    {
        const float4* Xv = reinterpret_cast<const float4*>(X + (size_t)b0 * DDIM);
        #pragma unroll
        for (int it = 0; it < 16; ++it) {
            int idx4 = tid + it * 256;
            int r = idx4 >> 6, c4 = idx4 & 63;
            float4 v = Xv[r * 64 + c4];
            uint2 p;
            p.x = (unsigned)f2bf(v.x) | ((unsigned)f2bf(v.y) << 16);
            p.y = (unsigned)f2bf(v.z) | ((unsigned)f2bf(v.w) << 16);
            int byte = (r * 512 + c4 * 8) ^ ((r & 7) << 4);
            *reinterpret_cast<uint2*>(&Xl[byte]) = p;
        }
    }
    f32x4 acc[4][4];
    #pragma unroll
    for (int nf = 0; nf < 4; ++nf) {
        int j = wv * 64 + nf * 16 + r15;
        float vj = Wn[(size_t)j * WROW + 256] + Wn[65792 + j];
        #pragma unroll
        for (int m = 0; m < 4; ++m) acc[m][nf] = f32x4{vj, vj, vj, vj};
    }
    auto stageW = [&](int buf, int kk) {
        const int k0 = kk * 32;
        const int j  = tid;
        float t[32];
        #pragma unroll
        for (int k = 0; k < 32; ++k) t[k] = Wn[(size_t)(k0 + k) * WROW + j];
        char* Wb = Wl[buf];
        #pragma unroll
        for (int g = 0; g < 4; ++g) {
            unsigned int p0 = (unsigned)f2bf(t[g*8+0]) | ((unsigned)f2bf(t[g*8+1]) << 16);
            unsigned int p1 = (unsigned)f2bf(t[g*8+2]) | ((unsigned)f2bf(t[g*8+3]) << 16);
            unsigned int p2 = (unsigned)f2bf(t[g*8+4]) | ((unsigned)f2bf(t[g*8+5]) << 16);
            unsigned int p3 = (unsigned)f2bf(t[g*8+6]) | ((unsigned)f2bf(t[g*8+7]) << 16);
            int byte = (j * 64 + g * 16) ^ ((j & 7) << 4);
            *reinterpret_cast<uint4*>(&Wb[byte]) = make_uint4(p0, p1, p2, p3);
        }
    };
    auto computeK = [&](int buf, int kk) {
        char* Wb = Wl[buf];
        short8 a[4], bbf[4];
        #pragma unroll
        for (int m = 0; m < 4; ++m) {
            int row = m * 16 + r15;
            int byte = (row * 512 + kk * 64 + qw * 16) ^ ((row & 7) << 4);
            a[m] = *reinterpret_cast<short8*>(&Xl[byte]);
        }
        #pragma unroll
        for (int nf = 0; nf < 4; ++nf) {
            int j = wv * 64 + nf * 16 + r15;
            int byte = (j * 64 + qw * 16) ^ ((j & 7) << 4);
            bbf[nf] = *reinterpret_cast<short8*>(&Wb[byte]);
        }
        #pragma unroll
        for (int m = 0; m < 4; ++m)
            #pragma unroll
            for (int nf = 0; nf < 4; ++nf)
                acc[m][nf] = __builtin_amdgcn_mfma_f32_16x16x32_bf16(a[m], bbf[nf], acc[m][nf], 0, 0, 0);
    };
    stageW(0, 0);
    int cur = 0;
    #pragma unroll
    for (int kk = 0; kk < 8; ++kk) {
        __syncthreads();
        if (kk < 7) stageW(cur ^ 1, kk + 1);
        computeK(cur, kk);
        cur ^= 1;
    }
    float ps[16];
    #pragma unroll
    for (int i = 0; i < 16; ++i) ps[i] = 0.f;
    #pragma unroll
    for (int m = 0; m < 4; ++m)
        #pragma unroll
        for (int nf = 0; nf < 4; ++nf) {
            int j = wv * 64 + nf * 16 + r15;
            #pragma unroll
            for (int r = 0; r < 4; ++r) {
                int brow = m * 16 + qw * 4 + r;
                int byte = (brow * 512 + j * 2) ^ ((brow & 7) << 4);
                float xv = bf2f(*reinterpret_cast<unsigned short*>(&Xl[byte]));
                ps[m * 4 + r] += acc[m][nf][r] * xv;
            }
        }
    #pragma unroll
    for (int off = 1; off <= 8; off <<= 1)
        #pragma unroll
        for (int i = 0; i < 16; ++i) ps[i] += __shfl_xor(ps[i], off, 64);
    __syncthreads();
    float* red = reinterpret_cast<float*>(Wl);
    if (r15 == 0) {
        #pragma unroll
        for (int m = 0; m < 4; ++m)
            #pragma unroll
            for (int r = 0; r < 4; ++r)
                red[wv * 64 + m * 16 + qw * 4 + r] = ps[m * 4 + r];
    }
    __syncthreads();
    if (tid < 64) {
        float s = red[tid] + red[64 + tid] + red[128 + tid] + red[192 + tid] + Wn[66048];
        H[(size_t)(b0 + tid) * DDIM + n] = s;
    }
}

__global__ __launch_bounds__(256) void out_kernel(
    const float* __restrict__ H, const float* __restrict__ w_out,
    const float* __restrict__ b_out, float* __restrict__ out)
{
    int b = blockIdx.x * 4 + (threadIdx.x >> 6);
    int lane = threadIdx.x & 63;
    const float* h = H + (size_t)b * 256;
    float s = 0.f;
    #pragma unroll
    for (int c = 0; c < 4; ++c) s += h[lane + c * 64] * w_out[lane + c * 64];
    #pragma unroll
    for (int off = 1; off < 64; off <<= 1) s += __shfl_xor(s, off, 64);
    if (lane == 0) out[b] = s + b_out[0];
}

extern "C" void kernel_launch(void* const* d_in, const int* in_sizes, int n_in,
                              void* d_out, int out_size, void* d_ws, size_t ws_size,
                              hipStream_t stream) {
    const float* x    = (const float*)d_in[0];
    const float* W1   = (const float*)d_in[1];
    const float* W2   = (const float*)d_in[2];
    const float* W3   = (const float*)d_in[3];
    const float* wout = (const float*)d_in[4];
    const float* bout = (const float*)d_in[5];
    float* out = (float*)d_out;

    const size_t WT_BYTES  = (size_t)256 * 256 * 256 * 2;  // 33.55 MB
    const size_t XB_BYTES  = (size_t)2048 * 256 * 2;       // 1 MB
    const size_t XE2_BYTES = (size_t)32 * 16384 * 2;       // 1 MB
    const size_t VT_BYTES  = 256 * 256 * 4;                // 256 KB
    const size_t DV_BYTES  = 1024;
    const size_t HT_BYTES  = (size_t)256 * 2048 * 2;       // 1 MB (single buffer: pn never reads Ht)
    const size_t need = WT_BYTES + XB_BYTES + XE2_BYTES + VT_BYTES + DV_BYTES + HT_BYTES; // ~36.96 MB

    dim3 blk(256, 1, 1);

    if (ws_size >= need) {
        char* p = (char*)d_ws;
        unsigned short* Wt2 = (unsigned short*)p;              p += WT_BYTES;
        unsigned short* Xbf = (unsigned short*)p;              p += XB_BYTES;
        unsigned short* Xe2 = (unsigned short*)p;              p += XE2_BYTES;
        float*          Vt  = (float*)p;                       p += VT_BYTES;
        float*          Dv  = (float*)p;                       p += DV_BYTES;
        unsigned short* Ht  = (unsigned short*)p;

        const float* Ws[3] = {W1, W2, W3};

        dim3 wgrid(10, 256), lgrid(32, 64), xgrid(16);
        for (int L = 0; L < 3; ++L) {
            if (L == 0) conv_x_rm_kernel<<<xgrid, blk, 0, stream>>>(x, Xbf, Xe2);
            else        conv_x_tr_kernel<<<xgrid, blk, 0, stream>>>(Ht, Xbf, Xe2);
            conv_w2_kernel<<<wgrid, blk, 0, stream>>>(Ws[L], Wt2);
            conv_v_kernel<<<dim3(256), blk, 0, stream>>>(Ws[L], Vt, Dv);
            pn6_kernel<<<lgrid, blk, 0, stream>>>(Xbf, Xe2, Wt2, Vt, Dv, Ht);
        }
        out_tr_kernel<<<xgrid, blk, 0, stream>>>(Ht, wout, bout, out);
    } else {
        float* h1 = (float*)d_ws;
        float* h2 = h1 + 2048 * 256;
        dim3 grid(32, 256);
        pn_layer_kernel<<<grid, blk, 0, stream>>>(x,  W1, h1);
        pn_layer_kernel<<<grid, blk, 0, stream>>>(h1, W2, h2);
        pn_layer_kernel<<<grid, blk, 0, stream>>>(h2, W3, h1);
        out_kernel<<<512, blk, 0, stream>>>(h1, wout, bout, out);
    }
}

// Round 9
// 781.132 us; speedup vs baseline: 2.5921x; 1.6347x over previous
//
#include <hip/hip_runtime.h>
#include <hip/hip_bf16.h>

typedef __attribute__((ext_vector_type(8))) short short8;   // 8 bf16 (4 VGPRs) — MFMA A/B frag
typedef __attribute__((ext_vector_type(4))) float f32x4;    // MFMA C/D frag

#define DDIM 256
#define WROW 257
#define WSTRIDE 66049  // 257*257

__device__ __forceinline__ unsigned short f2bf(float f) {
    unsigned int u = __float_as_uint(f);
    u += 0x7fff + ((u >> 16) & 1);   // RNE (finite values)
    return (unsigned short)(u >> 16);
}
__device__ __forceinline__ float bf2f(unsigned short s) {
    return __uint_as_float(((unsigned int)s) << 16);
}

// ======================= FAST PATH =======================

// Symmetrized, pre-scaled, transposed W:
//   Wt2[n][j][k] = s * (A[k][j] + A[j][k]),  s = 1 for k32<j32, 0.5 for k32==j32
__global__ __launch_bounds__(256) void conv_w2_kernel(
    const float* __restrict__ Wf, unsigned short* __restrict__ Wt2)
{
    __shared__ float tKJ[64][65];
    __shared__ float tJK[64][65];
    const int TJ[10] = {0,1,1,2,2,2,3,3,3,3};
    const int TK[10] = {0,0,1,0,1,2,0,1,2,3};
    const int tid = threadIdx.x;
    const int n   = blockIdx.y;
    const int tj  = TJ[blockIdx.x];
    const int tk  = TK[blockIdx.x];
    const float* Wn = Wf + (size_t)n * WSTRIDE;
    #pragma unroll
    for (int it = 0; it < 16; ++it) {
        int r = it * 4 + (tid >> 6);
        int c = tid & 63;
        tKJ[r][c] = Wn[(size_t)(tk * 64 + r) * WROW + tj * 64 + c];
        tJK[r][c] = Wn[(size_t)(tj * 64 + r) * WROW + tk * 64 + c];
    }
    __syncthreads();
    unsigned short* out = Wt2 + ((size_t)n << 16);
    #pragma unroll
    for (int it = 0; it < 8; ++it) {
        int jl = it * 8 + (tid >> 5);
        int k2 = (tid & 31) * 2;
        int p32 = tk * 2 + (k2 >> 5);
        int q32 = tj * 2 + (jl >> 5);
        if (p32 <= q32) {
            float sc = (p32 == q32) ? 0.5f : 1.0f;
            float v0 = sc * (tKJ[k2][jl]     + tJK[jl][k2]);
            float v1 = sc * (tKJ[k2 + 1][jl] + tJK[jl][k2 + 1]);
            unsigned int u = (unsigned)f2bf(v0) | ((unsigned)f2bf(v1) << 16);
            *reinterpret_cast<unsigned int*>(out + (size_t)(tj * 64 + jl) * 256 + tk * 64 + k2) = u;
        }
    }
}

// Vt[n][j] = W[n][j][256] + W[n][256][j];  Dv[n] = W[n][256][256]
__global__ void conv_v_kernel(const float* __restrict__ Wf,
                              float* __restrict__ Vt, float* __restrict__ Dv)
{
    int n = blockIdx.x, j = threadIdx.x;
    const float* Wn = Wf + (size_t)n * WSTRIDE;
    Vt[n * 256 + j] = Wn[(size_t)j * WROW + 256] + Wn[65792 + j];
    if (j == 0) Dv[n] = Wn[66048];
}

// Epilogue gather: Xe2[bt][jt][m][lane] = short8 { x[row(m,qw,r)][jA] r=0..3, x[row][jB] r=0..3 }
//   jA = jt*32 + r15, jB = jA+16, row = m*16 + qw*4 + r (bt-local).  Lane-only-dependent.
__device__ __forceinline__ void xe_gather3(const unsigned short* T, unsigned short* Xe2,
                                           int bx, int tid) {
    const int lane = tid & 63, g = tid >> 6, qw = (tid >> 4) & 3, r15 = tid & 15;
    #pragma unroll
    for (int it = 0; it < 16; ++it) {
        int c  = g * 16 + it;        // flat (h, jt, m) in [0,64)
        int h  = c >> 5;
        int jt = (c >> 2) & 7;
        int m  = c & 3;
        int rbase = h * 64 + m * 16 + qw * 4;
        int jA = jt * 32 + r15;
        unsigned int u0 = T[(rbase + 0) * 256 + jA];
        unsigned int u1 = T[(rbase + 1) * 256 + jA];
        unsigned int u2 = T[(rbase + 2) * 256 + jA];
        unsigned int u3 = T[(rbase + 3) * 256 + jA];
        unsigned int v0 = T[(rbase + 0) * 256 + jA + 16];
        unsigned int v1 = T[(rbase + 1) * 256 + jA + 16];
        unsigned int v2 = T[(rbase + 2) * 256 + jA + 16];
        unsigned int v3 = T[(rbase + 3) * 256 + jA + 16];
        uint4 w = make_uint4(u0 | (u1 << 16), u2 | (u3 << 16),
                             v0 | (v1 << 16), v2 | (v3 << 16));
        *reinterpret_cast<uint4*>(Xe2 + ((size_t)(bx * 2 + h) * 16384 + jt * 2048 + m * 512 + lane * 8)) = w;
    }
}

// Layer-1 input prep: X f32 row-major -> Xbf (bf16 row-major) + Xe2
__global__ __launch_bounds__(256) void conv_x_rm_kernel(
    const float* __restrict__ X, unsigned short* __restrict__ Xbf, unsigned short* __restrict__ Xe2)
{
    __shared__ __align__(16) unsigned short T[128 * 256];
    const int tid = threadIdx.x;
    const int b0 = blockIdx.x * 128;
    const float4* Xv = reinterpret_cast<const float4*>(X + (size_t)b0 * 256);
    uint2* Xo = reinterpret_cast<uint2*>(Xbf + (size_t)b0 * 256);
    #pragma unroll
    for (int it = 0; it < 32; ++it) {
        int idx4 = it * 256 + tid;
        float4 v = Xv[idx4];
        uint2 p;
        p.x = (unsigned)f2bf(v.x) | ((unsigned)f2bf(v.y) << 16);
        p.y = (unsigned)f2bf(v.z) | ((unsigned)f2bf(v.w) << 16);
        *reinterpret_cast<uint2*>(&T[idx4 * 4]) = p;
        Xo[idx4] = p;
    }
    __syncthreads();
    xe_gather3(T, Xe2, blockIdx.x, tid);
}

// Layer-2/3 input prep: Ht bf16 [256][2048] (k-major) -> Xbf row-major + Xe2
__global__ __launch_bounds__(256) void conv_x_tr_kernel(
    const unsigned short* __restrict__ Hsrc, unsigned short* __restrict__ Xbf,
    unsigned short* __restrict__ Xe2)
{
    __shared__ __align__(16) unsigned short T[128 * 256];
    const int tid = threadIdx.x;
    const int b0 = blockIdx.x * 128;
    #pragma unroll
    for (int it = 0; it < 64; ++it) {
        int lin = it * 256 + tid;
        int k = lin >> 6, bp = lin & 63;
        unsigned int v = *reinterpret_cast<const unsigned int*>(Hsrc + (size_t)k * 2048 + b0 + bp * 2);
        T[(bp * 2) * 256 + k]     = (unsigned short)(v & 0xffff);
        T[(bp * 2 + 1) * 256 + k] = (unsigned short)(v >> 16);
    }
    __syncthreads();
    uint4* Xo = reinterpret_cast<uint4*>(Xbf + (size_t)b0 * 256);
    #pragma unroll
    for (int it = 0; it < 16; ++it) {   // 4096 uint4 per 128x256 tile
        int idx8 = it * 256 + tid;
        Xo[idx8] = *reinterpret_cast<uint4*>(&T[idx8 * 8]);
    }
    xe_gather3(T, Xe2, blockIdx.x, tid);
}

// pn6: block = 4 waves, BM=64; wave wv computes the FULL triangle for n = ng*4+wv.
// One barrier total; waves independent afterwards.
// launch_bounds min-waves=2: min-waves=3 splits the unified file 84 arch + 84 acc
// and the kk-loop needs ~120 arch regs -> structural spill (R7/R8: 1.0-1.5 GB/dispatch
// scratch traffic at identical VGPR_Count=84). (256,2) = 256-reg cap, proven no-spill.
__global__ __launch_bounds__(256, 2) void pn6_kernel(
    const unsigned short* __restrict__ Xbf,  // [2048][256] bf16 row-major
    const unsigned short* __restrict__ Xe2,  // [32][8][4][64] short8 epilogue gather
    const unsigned short* __restrict__ Wt2,  // [256][256][256] bf16 symmetric triangle, j-major
    const float* __restrict__ Vt,            // [256][256] v
    const float* __restrict__ Dv,            // [256] d
    unsigned short* __restrict__ Ht)         // [256][2048] bf16
{
    __shared__ __align__(16) char Xl[32768];  // bf16 [64][256], XOR-swizzled

    const int tid  = threadIdx.x;
    const int lane = tid & 63;
    const int wv   = tid >> 6;
    const int qw   = lane >> 4;
    const int r15  = lane & 15;

    // fid -> (ng, bt): XCD k (fid%8) handles ng === k (mod 8) -> 32 n per XCD,
    // W working set ~2.3 MB < 4 MB L2, re-read by the 32 bt-blocks on that XCD.
    const int fid = blockIdx.y * 32 + blockIdx.x;
    const int bt  = (fid >> 3) & 31;
    const int ng  = (fid & 7) + ((fid >> 8) << 3);
    const int n   = ng * 4 + wv;
    const int b0  = bt * 64;

    // ---- stage bf16 X tile (32 KB) with write-side XOR swizzle ----
    {
        const uint4* xs = reinterpret_cast<const uint4*>(Xbf + (size_t)b0 * 256);
        #pragma unroll
        for (int c = 0; c < 8; ++c) {
            int idx = c * 256 + tid;
            uint4 v = xs[idx];
            int L = idx * 16;
            int d = L ^ (((L >> 9) & 7) << 4);
            *reinterpret_cast<uint4*>(&Xl[d]) = v;
        }
    }

    const unsigned short* Wn = Wt2 + ((size_t)n << 16);
    const float* vn = Vt + n * 256;
    const unsigned short* xe = Xe2 + (size_t)bt * 16384 + lane * 8;

    float ps[4][4];
    #pragma unroll
    for (int m = 0; m < 4; ++m)
        #pragma unroll
        for (int r = 0; r < 4; ++r) ps[m][r] = 0.f;

    __syncthreads();

    for (int jt = 0; jt < 8; ++jt) {
        const unsigned short* pA = Wn + (size_t)(jt * 32 + r15) * 256 + qw * 8;
        const unsigned short* pB = pA + 16 * 256;
        const float vA = vn[jt * 32 + r15];
        const float vB = vn[jt * 32 + 16 + r15];
        short8 c0 = *reinterpret_cast<const short8*>(pA);
        short8 c1 = *reinterpret_cast<const short8*>(pB);

        f32x4 a0[4], a1[4];
        #pragma unroll
        for (int m = 0; m < 4; ++m) {
            a0[m] = f32x4{vA, vA, vA, vA};
            a1[m] = f32x4{vB, vB, vB, vB};
        }
        for (int kk = 0; kk <= jt; ++kk) {
            short8 nx0, nx1;
            const bool more = kk < jt;
            if (more) {
                nx0 = *reinterpret_cast<const short8*>(pA + (kk + 1) * 32);
                nx1 = *reinterpret_cast<const short8*>(pB + (kk + 1) * 32);
            }
            #pragma unroll
            for (int m = 0; m < 4; ++m) {
                const int row = m * 16 + r15;
                const int byte = (row * 512 + kk * 64 + qw * 16) ^ ((row & 7) << 4);
                short8 a = *reinterpret_cast<const short8*>(&Xl[byte]);
                a0[m] = __builtin_amdgcn_mfma_f32_16x16x32_bf16(a, c0, a0[m], 0, 0, 0);
                a1[m] = __builtin_amdgcn_mfma_f32_16x16x32_bf16(a, c1, a1[m], 0, 0, 0);
            }
            if (more) { c0 = nx0; c1 = nx1; }
        }
        // contraction: ps += C .* x  (j-cols of this jt), e loaded directly (L2-hot)
        #pragma unroll
        for (int m = 0; m < 4; ++m) {
            short8 e = *reinterpret_cast<const short8*>(xe + jt * 2048 + m * 512);
            #pragma unroll
            for (int r = 0; r < 4; ++r)
                ps[m][r] += a0[m][r] * bf2f((unsigned short)e[r])
                          + a1[m][r] * bf2f((unsigned short)e[4 + r]);
        }
    }

    // reduce over the 16 j-lanes (r15 bits)
    #pragma unroll
    for (int off = 1; off <= 8; off <<= 1)
        #pragma unroll
        for (int m = 0; m < 4; ++m)
            #pragma unroll
            for (int r = 0; r < 4; ++r) ps[m][r] += __shfl_xor(ps[m][r], off, 64);

    if (r15 == 0) {
        const float dn = Dv[n];
        #pragma unroll
        for (int m = 0; m < 4; ++m)
            #pragma unroll
            for (int r = 0; r < 4; ++r)
                Ht[(size_t)n * 2048 + b0 + m * 16 + qw * 4 + r] = f2bf(ps[m][r] + dn);
    }
}

__global__ __launch_bounds__(256) void out_tr_kernel(
    const unsigned short* __restrict__ H3, const float* __restrict__ w_out,
    const float* __restrict__ b_out, float* __restrict__ out)
{
    __shared__ float red2[256];
    const int tid = threadIdx.x;
    const int b = blockIdx.x * 128 + (tid & 127);
    const int half = tid >> 7;
    float s = 0.f;
    #pragma unroll 8
    for (int k = 0; k < 128; ++k) {
        int nn = half * 128 + k;
        s += bf2f(H3[(size_t)nn * 2048 + b]) * w_out[nn];
    }
    red2[tid] = s;
    __syncthreads();
    if (tid < 128) out[b] = red2[tid] + red2[tid + 128] + b_out[0];
}

// ======================= FALLBACK PATH (small ws) =======================

__global__ __launch_bounds__(256, 2) void pn_layer_kernel(
    const float* __restrict__ X, const float* __restrict__ W, float* __restrict__ H)
{
    __shared__ __align__(16) char Xl[64 * 256 * 2];
    __shared__ __align__(16) char Wl[2][256 * 32 * 2];
    const int tid  = threadIdx.x;
    const int lane = tid & 63;
    const int wv   = tid >> 6;
    const int qw   = lane >> 4;
    const int r15  = lane & 15;
    const int n  = blockIdx.y;
    const int b0 = blockIdx.x * 64;
    const float* Wn = W + (size_t)n * WSTRIDE;
    {
        const float4* Xv = reinterpret_cast<const float4*>(X + (size_t)b0 * DDIM);
        #pragma unroll
        for (int it = 0; it < 16; ++it) {
            int idx4 = tid + it * 256;
            int r = idx4 >> 6, c4 = idx4 & 63;
            float4 v = Xv[r * 64 + c4];
            uint2 p;
            p.x = (unsigned)f2bf(v.x) | ((unsigned)f2bf(v.y) << 16);
            p.y = (unsigned)f2bf(v.z) | ((unsigned)f2bf(v.w) << 16);
            int byte = (r * 512 + c4 * 8) ^ ((r & 7) << 4);
            *reinterpret_cast<uint2*>(&Xl[byte]) = p;
        }
    }
    f32x4 acc[4][4];
    #pragma unroll
    for (int nf = 0; nf < 4; ++nf) {
        int j = wv * 64 + nf * 16 + r15;
        float vj = Wn[(size_t)j * WROW + 256] + Wn[65792 + j];
        #pragma unroll
        for (int m = 0; m < 4; ++m) acc[m][nf] = f32x4{vj, vj, vj, vj};
    }
    auto stageW = [&](int buf, int kk) {
        const int k0 = kk * 32;
        const int j  = tid;
        float t[32];
        #pragma unroll
        for (int k = 0; k < 32; ++k) t[k] = Wn[(size_t)(k0 + k) * WROW + j];
        char* Wb = Wl[buf];
        #pragma unroll
        for (int g = 0; g < 4; ++g) {
            unsigned int p0 = (unsigned)f2bf(t[g*8+0]) | ((unsigned)f2bf(t[g*8+1]) << 16);
            unsigned int p1 = (unsigned)f2bf(t[g*8+2]) | ((unsigned)f2bf(t[g*8+3]) << 16);
            unsigned int p2 = (unsigned)f2bf(t[g*8+4]) | ((unsigned)f2bf(t[g*8+5]) << 16);
            unsigned int p3 = (unsigned)f2bf(t[g*8+6]) | ((unsigned)f2bf(t[g*8+7]) << 16);
            int byte = (j * 64 + g * 16) ^ ((j & 7) << 4);
            *reinterpret_cast<uint4*>(&Wb[byte]) = make_uint4(p0, p1, p2, p3);
        }
    };
    auto computeK = [&](int buf, int kk) {
        char* Wb = Wl[buf];
        short8 a[4], bbf[4];
        #pragma unroll
        for (int m = 0; m < 4; ++m) {
            int row = m * 16 + r15;
            int byte = (row * 512 + kk * 64 + qw * 16) ^ ((row & 7) << 4);
            a[m] = *reinterpret_cast<short8*>(&Xl[byte]);
        }
        #pragma unroll
        for (int nf = 0; nf < 4; ++nf) {
            int j = wv * 64 + nf * 16 + r15;
            int byte = (j * 64 + qw * 16) ^ ((j & 7) << 4);
            bbf[nf] = *reinterpret_cast<short8*>(&Wb[byte]);
        }
        #pragma unroll
        for (int m = 0; m < 4; ++m)
            #pragma unroll
            for (int nf = 0; nf < 4; ++nf)
                acc[m][nf] = __builtin_amdgcn_mfma_f32_16x16x32_bf16(a[m], bbf[nf], acc[m][nf], 0, 0, 0);
    };
    stageW(0, 0);
    int cur = 0;
    #pragma unroll
    for (int kk = 0; kk < 8; ++kk) {
        __syncthreads();
        if (kk < 7) stageW(cur ^ 1, kk + 1);
        computeK(cur, kk);
        cur ^= 1;
    }
    float ps[16];
    #pragma unroll
    for (int i = 0; i < 16; ++i) ps[i] = 0.f;
    #pragma unroll
    for (int m = 0; m < 4; ++m)
        #pragma unroll
        for (int nf = 0; nf < 4; ++nf) {
            int j = wv * 64 + nf * 16 + r15;
            #pragma unroll
            for (int r = 0; r < 4; ++r) {
                int brow = m * 16 + qw * 4 + r;
                int byte = (brow * 512 + j * 2) ^ ((brow & 7) << 4);
                float xv = bf2f(*reinterpret_cast<unsigned short*>(&Xl[byte]));
                ps[m * 4 + r] += acc[m][nf][r] * xv;
            }
        }
    #pragma unroll
    for (int off = 1; off <= 8; off <<= 1)
        #pragma unroll
        for (int i = 0; i < 16; ++i) ps[i] += __shfl_xor(ps[i], off, 64);
    __syncthreads();
    float* red = reinterpret_cast<float*>(Wl);
    if (r15 == 0) {
        #pragma unroll
        for (int m = 0; m < 4; ++m)
            #pragma unroll
            for (int r = 0; r < 4; ++r)
                red[wv * 64 + m * 16 + qw * 4 + r] = ps[m * 4 + r];
    }
    __syncthreads();
    if (tid < 64) {
        float s = red[tid] + red[64 + tid] + red[128 + tid] + red[192 + tid] + Wn[66048];
        H[(size_t)(b0 + tid) * DDIM + n] = s;
    }
}

__global__ __launch_bounds__(256) void out_kernel(
    const float* __restrict__ H, const float* __restrict__ w_out,
    const float* __restrict__ b_out, float* __restrict__ out)
{
    int b = blockIdx.x * 4 + (threadIdx.x >> 6);
    int lane = threadIdx.x & 63;
    const float* h = H + (size_t)b * 256;
    float s = 0.f;
    #pragma unroll
    for (int c = 0; c < 4; ++c) s += h[lane + c * 64] * w_out[lane + c * 64];
    #pragma unroll
    for (int off = 1; off < 64; off <<= 1) s += __shfl_xor(s, off, 64);
    if (lane == 0) out[b] = s + b_out[0];
}

extern "C" void kernel_launch(void* const* d_in, const int* in_sizes, int n_in,
                              void* d_out, int out_size, void* d_ws, size_t ws_size,
                              hipStream_t stream) {
    const float* x    = (const float*)d_in[0];
    const float* W1   = (const float*)d_in[1];
    const float* W2   = (const float*)d_in[2];
    const float* W3   = (const float*)d_in[3];
    const float* wout = (const float*)d_in[4];
    const float* bout = (const float*)d_in[5];
    float* out = (float*)d_out;

    const size_t WT_BYTES  = (size_t)256 * 256 * 256 * 2;  // 33.55 MB
    const size_t XB_BYTES  = (size_t)2048 * 256 * 2;       // 1 MB
    const size_t XE2_BYTES = (size_t)32 * 16384 * 2;       // 1 MB
    const size_t VT_BYTES  = 256 * 256 * 4;                // 256 KB
    const size_t DV_BYTES  = 1024;
    const size_t HT_BYTES  = (size_t)256 * 2048 * 2;       // 1 MB (single buffer: pn never reads Ht)
    const size_t need = WT_BYTES + XB_BYTES + XE2_BYTES + VT_BYTES + DV_BYTES + HT_BYTES; // ~36.96 MB

    dim3 blk(256, 1, 1);

    if (ws_size >= need) {
        char* p = (char*)d_ws;
        unsigned short* Wt2 = (unsigned short*)p;              p += WT_BYTES;
        unsigned short* Xbf = (unsigned short*)p;              p += XB_BYTES;
        unsigned short* Xe2 = (unsigned short*)p;              p += XE2_BYTES;
        float*          Vt  = (float*)p;                       p += VT_BYTES;
        float*          Dv  = (float*)p;                       p += DV_BYTES;
        unsigned short* Ht  = (unsigned short*)p;

        const float* Ws[3] = {W1, W2, W3};

        dim3 wgrid(10, 256), lgrid(32, 64), xgrid(16);
        for (int L = 0; L < 3; ++L) {
            if (L == 0) conv_x_rm_kernel<<<xgrid, blk, 0, stream>>>(x, Xbf, Xe2);
            else        conv_x_tr_kernel<<<xgrid, blk, 0, stream>>>(Ht, Xbf, Xe2);
            conv_w2_kernel<<<wgrid, blk, 0, stream>>>(Ws[L], Wt2);
            conv_v_kernel<<<dim3(256), blk, 0, stream>>>(Ws[L], Vt, Dv);
            pn6_kernel<<<lgrid, blk, 0, stream>>>(Xbf, Xe2, Wt2, Vt, Dv, Ht);
        }
        out_tr_kernel<<<xgrid, blk, 0, stream>>>(Ht, wout, bout, out);
    } else {
        float* h1 = (float*)d_ws;
        float* h2 = h1 + 2048 * 256;
        dim3 grid(32, 256);
        pn_layer_kernel<<<grid, blk, 0, stream>>>(x,  W1, h1);
        pn_layer_kernel<<<grid, blk, 0, stream>>>(h1, W2, h2);
        pn_layer_kernel<<<grid, blk, 0, stream>>>(h2, W3, h1);
        out_kernel<<<512, blk, 0, stream>>>(h1, wout, bout, out);
    }
}

// Round 10
// 356.728 us; speedup vs baseline: 5.6761x; 2.1897x over previous
//
#include <hip/hip_runtime.h>
#include <hip/hip_bf16.h>

typedef __attribute__((ext_vector_type(8))) short short8;   // 8 bf16 (4 VGPRs) — MFMA A/B frag
typedef __attribute__((ext_vector_type(4))) float f32x4;    // MFMA C/D frag

#define DDIM 256
#define WROW 257
#define WSTRIDE 66049  // 257*257

__device__ __forceinline__ unsigned short f2bf(float f) {
    unsigned int u = __float_as_uint(f);
    u += 0x7fff + ((u >> 16) & 1);   // RNE (finite values)
    return (unsigned short)(u >> 16);
}
__device__ __forceinline__ float bf2f(unsigned short s) {
    return __uint_as_float(((unsigned int)s) << 16);
}

// ======================= FAST PATH =======================

// Symmetrized, pre-scaled, transposed W:
//   Wt2[n][j][k] = s * (A[k][j] + A[j][k]),  s = 1 for k32<j32, 0.5 for k32==j32
__global__ __launch_bounds__(256) void conv_w2_kernel(
    const float* __restrict__ Wf, unsigned short* __restrict__ Wt2)
{
    __shared__ float tKJ[64][65];
    __shared__ float tJK[64][65];
    const int TJ[10] = {0,1,1,2,2,2,3,3,3,3};
    const int TK[10] = {0,0,1,0,1,2,0,1,2,3};
    const int tid = threadIdx.x;
    const int n   = blockIdx.y;
    const int tj  = TJ[blockIdx.x];
    const int tk  = TK[blockIdx.x];
    const float* Wn = Wf + (size_t)n * WSTRIDE;
    #pragma unroll
    for (int it = 0; it < 16; ++it) {
        int r = it * 4 + (tid >> 6);
        int c = tid & 63;
        tKJ[r][c] = Wn[(size_t)(tk * 64 + r) * WROW + tj * 64 + c];
        tJK[r][c] = Wn[(size_t)(tj * 64 + r) * WROW + tk * 64 + c];
    }
    __syncthreads();
    unsigned short* out = Wt2 + ((size_t)n << 16);
    #pragma unroll
    for (int it = 0; it < 8; ++it) {
        int jl = it * 8 + (tid >> 5);
        int k2 = (tid & 31) * 2;
        int p32 = tk * 2 + (k2 >> 5);
        int q32 = tj * 2 + (jl >> 5);
        if (p32 <= q32) {
            float sc = (p32 == q32) ? 0.5f : 1.0f;
            float v0 = sc * (tKJ[k2][jl]     + tJK[jl][k2]);
            float v1 = sc * (tKJ[k2 + 1][jl] + tJK[jl][k2 + 1]);
            unsigned int u = (unsigned)f2bf(v0) | ((unsigned)f2bf(v1) << 16);
            *reinterpret_cast<unsigned int*>(out + (size_t)(tj * 64 + jl) * 256 + tk * 64 + k2) = u;
        }
    }
}

// Vt[n][j] = W[n][j][256] + W[n][256][j];  Dv[n] = W[n][256][256]
__global__ void conv_v_kernel(const float* __restrict__ Wf,
                              float* __restrict__ Vt, float* __restrict__ Dv)
{
    int n = blockIdx.x, j = threadIdx.x;
    const float* Wn = Wf + (size_t)n * WSTRIDE;
    Vt[n * 256 + j] = Wn[(size_t)j * WROW + 256] + Wn[65792 + j];
    if (j == 0) Dv[n] = Wn[66048];
}

// Epilogue gather: Xe2[bt][jt][m][lane] = short8 { x[row(m,qw,r)][jA] r=0..3, x[row][jB] r=0..3 }
//   jA = jt*32 + r15, jB = jA+16, row = m*16 + qw*4 + r (bt-local).  Lane-only-dependent.
__device__ __forceinline__ void xe_gather3(const unsigned short* T, unsigned short* Xe2,
                                           int bx, int tid) {
    const int lane = tid & 63, g = tid >> 6, qw = (tid >> 4) & 3, r15 = tid & 15;
    #pragma unroll
    for (int it = 0; it < 16; ++it) {
        int c  = g * 16 + it;        // flat (h, jt, m) in [0,64)
        int h  = c >> 5;
        int jt = (c >> 2) & 7;
        int m  = c & 3;
        int rbase = h * 64 + m * 16 + qw * 4;
        int jA = jt * 32 + r15;
        unsigned int u0 = T[(rbase + 0) * 256 + jA];
        unsigned int u1 = T[(rbase + 1) * 256 + jA];
        unsigned int u2 = T[(rbase + 2) * 256 + jA];
        unsigned int u3 = T[(rbase + 3) * 256 + jA];
        unsigned int v0 = T[(rbase + 0) * 256 + jA + 16];
        unsigned int v1 = T[(rbase + 1) * 256 + jA + 16];
        unsigned int v2 = T[(rbase + 2) * 256 + jA + 16];
        unsigned int v3 = T[(rbase + 3) * 256 + jA + 16];
        uint4 w = make_uint4(u0 | (u1 << 16), u2 | (u3 << 16),
                             v0 | (v1 << 16), v2 | (v3 << 16));
        *reinterpret_cast<uint4*>(Xe2 + ((size_t)(bx * 2 + h) * 16384 + jt * 2048 + m * 512 + lane * 8)) = w;
    }
}

// Layer-1 input prep: X f32 row-major -> Xbf (bf16 row-major) + Xe2
__global__ __launch_bounds__(256) void conv_x_rm_kernel(
    const float* __restrict__ X, unsigned short* __restrict__ Xbf, unsigned short* __restrict__ Xe2)
{
    __shared__ __align__(16) unsigned short T[128 * 256];
    const int tid = threadIdx.x;
    const int b0 = blockIdx.x * 128;
    const float4* Xv = reinterpret_cast<const float4*>(X + (size_t)b0 * 256);
    uint2* Xo = reinterpret_cast<uint2*>(Xbf + (size_t)b0 * 256);
    #pragma unroll
    for (int it = 0; it < 32; ++it) {
        int idx4 = it * 256 + tid;
        float4 v = Xv[idx4];
        uint2 p;
        p.x = (unsigned)f2bf(v.x) | ((unsigned)f2bf(v.y) << 16);
        p.y = (unsigned)f2bf(v.z) | ((unsigned)f2bf(v.w) << 16);
        *reinterpret_cast<uint2*>(&T[idx4 * 4]) = p;
        Xo[idx4] = p;
    }
    __syncthreads();
    xe_gather3(T, Xe2, blockIdx.x, tid);
}

// Layer-2/3 input prep: Ht bf16 [256][2048] (k-major) -> Xbf row-major + Xe2
__global__ __launch_bounds__(256) void conv_x_tr_kernel(
    const unsigned short* __restrict__ Hsrc, unsigned short* __restrict__ Xbf,
    unsigned short* __restrict__ Xe2)
{
    __shared__ __align__(16) unsigned short T[128 * 256];
    const int tid = threadIdx.x;
    const int b0 = blockIdx.x * 128;
    #pragma unroll
    for (int it = 0; it < 64; ++it) {
        int lin = it * 256 + tid;
        int k = lin >> 6, bp = lin & 63;
        unsigned int v = *reinterpret_cast<const unsigned int*>(Hsrc + (size_t)k * 2048 + b0 + bp * 2);
        T[(bp * 2) * 256 + k]     = (unsigned short)(v & 0xffff);
        T[(bp * 2 + 1) * 256 + k] = (unsigned short)(v >> 16);
    }
    __syncthreads();
    uint4* Xo = reinterpret_cast<uint4*>(Xbf + (size_t)b0 * 256);
    #pragma unroll
    for (int it = 0; it < 16; ++it) {   // 4096 uint4 per 128x256 tile
        int idx8 = it * 256 + tid;
        Xo[idx8] = *reinterpret_cast<uint4*>(&T[idx8 * 8]);
    }
    xe_gather3(T, Xe2, blockIdx.x, tid);
}

// pn7: block = 4 waves, BM=64; wave wv computes the FULL triangle for n = ng*4+wv.
// One barrier total; waves independent afterwards.
// KEY (R10): "#pragma unroll 1" on the jt loop. With trip count 8 known at compile
// time the compiler fully unrolled the 36-K-step triangle and hoisted ~108 global
// loads -> live-range explosion -> arch-half spill (R7-R9: 0.5-1.0 GB scratch
// writes/dispatch at VGPR_Count == exactly half the launch_bounds cap).
// Bounding the scheduling window to one jt keeps ~80 live arch regs < 128 cap.
__global__ __launch_bounds__(256, 2) void pn7_kernel(
    const unsigned short* __restrict__ Xbf,  // [2048][256] bf16 row-major
    const unsigned short* __restrict__ Xe2,  // [32][8][4][64] short8 epilogue gather
    const unsigned short* __restrict__ Wt2,  // [256][256][256] bf16 symmetric triangle, j-major
    const float* __restrict__ Vt,            // [256][256] v
    const float* __restrict__ Dv,            // [256] d
    unsigned short* __restrict__ Ht)         // [256][2048] bf16
{
    __shared__ __align__(16) char Xl[32768];  // bf16 [64][256], XOR-swizzled

    const int tid  = threadIdx.x;
    const int lane = tid & 63;
    const int wv   = tid >> 6;
    const int qw   = lane >> 4;
    const int r15  = lane & 15;

    // fid -> (ng, bt): XCD k (fid%8) handles ng === k (mod 8) -> 32 n per XCD,
    // W working set ~2.6 MB < 4 MB L2, re-read by the 32 bt-blocks on that XCD.
    const int fid = blockIdx.y * 32 + blockIdx.x;
    const int bt  = (fid >> 3) & 31;
    const int ng  = (fid & 7) + ((fid >> 8) << 3);
    const int n   = ng * 4 + wv;
    const int b0  = bt * 64;

    // ---- stage bf16 X tile (32 KB) with write-side XOR swizzle ----
    {
        const uint4* xs = reinterpret_cast<const uint4*>(Xbf + (size_t)b0 * 256);
        #pragma unroll
        for (int c = 0; c < 8; ++c) {
            int idx = c * 256 + tid;
            uint4 v = xs[idx];
            int L = idx * 16;
            int d = L ^ (((L >> 9) & 7) << 4);
            *reinterpret_cast<uint4*>(&Xl[d]) = v;
        }
    }

    const unsigned short* Wn = Wt2 + ((size_t)n << 16);
    const float* vn = Vt + n * 256;
    const unsigned short* xe = Xe2 + (size_t)bt * 16384 + lane * 8;

    float ps[4][4];
    #pragma unroll
    for (int m = 0; m < 4; ++m)
        #pragma unroll
        for (int r = 0; r < 4; ++r) ps[m][r] = 0.f;

    __syncthreads();

    #pragma unroll 1   // DO NOT fully unroll: bounds scheduler window, prevents spill
    for (int jt = 0; jt < 8; ++jt) {
        const unsigned short* pA = Wn + (size_t)(jt * 32 + r15) * 256 + qw * 8;
        const unsigned short* pB = pA + 16 * 256;
        const float vA = vn[jt * 32 + r15];
        const float vB = vn[jt * 32 + 16 + r15];
        short8 c0 = *reinterpret_cast<const short8*>(pA);
        short8 c1 = *reinterpret_cast<const short8*>(pB);

        f32x4 a0[4], a1[4];
        #pragma unroll
        for (int m = 0; m < 4; ++m) {
            a0[m] = f32x4{vA, vA, vA, vA};
            a1[m] = f32x4{vB, vB, vB, vB};
        }
        #pragma unroll 1
        for (int kk = 0; kk <= jt; ++kk) {
            short8 nx0, nx1;
            const bool more = kk < jt;
            if (more) {
                nx0 = *reinterpret_cast<const short8*>(pA + (kk + 1) * 32);
                nx1 = *reinterpret_cast<const short8*>(pB + (kk + 1) * 32);
            }
            #pragma unroll
            for (int m = 0; m < 4; ++m) {
                const int row = m * 16 + r15;
                const int byte = (row * 512 + kk * 64 + qw * 16) ^ ((row & 7) << 4);
                short8 a = *reinterpret_cast<const short8*>(&Xl[byte]);
                a0[m] = __builtin_amdgcn_mfma_f32_16x16x32_bf16(a, c0, a0[m], 0, 0, 0);
                a1[m] = __builtin_amdgcn_mfma_f32_16x16x32_bf16(a, c1, a1[m], 0, 0, 0);
            }
            if (more) { c0 = nx0; c1 = nx1; }
        }
        // contraction: ps += C .* x  (j-cols of this jt), e loaded directly (L2-hot)
        #pragma unroll
        for (int m = 0; m < 4; ++m) {
            short8 e = *reinterpret_cast<const short8*>(xe + jt * 2048 + m * 512);
            #pragma unroll
            for (int r = 0; r < 4; ++r)
                ps[m][r] += a0[m][r] * bf2f((unsigned short)e[r])
                          + a1[m][r] * bf2f((unsigned short)e[4 + r]);
        }
    }

    // reduce over the 16 j-lanes (r15 bits)
    #pragma unroll
    for (int off = 1; off <= 8; off <<= 1)
        #pragma unroll
        for (int m = 0; m < 4; ++m)
            #pragma unroll
            for (int r = 0; r < 4; ++r) ps[m][r] += __shfl_xor(ps[m][r], off, 64);

    if (r15 == 0) {
        const float dn = Dv[n];
        #pragma unroll
        for (int m = 0; m < 4; ++m)
            #pragma unroll
            for (int r = 0; r < 4; ++r)
                Ht[(size_t)n * 2048 + b0 + m * 16 + qw * 4 + r] = f2bf(ps[m][r] + dn);
    }
}

__global__ __launch_bounds__(256) void out_tr_kernel(
    const unsigned short* __restrict__ H3, const float* __restrict__ w_out,
    const float* __restrict__ b_out, float* __restrict__ out)
{
    __shared__ float red2[256];
    const int tid = threadIdx.x;
    const int b = blockIdx.x * 128 + (tid & 127);
    const int half = tid >> 7;
    float s = 0.f;
    #pragma unroll 8
    for (int k = 0; k < 128; ++k) {
        int nn = half * 128 + k;
        s += bf2f(H3[(size_t)nn * 2048 + b]) * w_out[nn];
    }
    red2[tid] = s;
    __syncthreads();
    if (tid < 128) out[b] = red2[tid] + red2[tid + 128] + b_out[0];
}

// ======================= FALLBACK PATH (small ws) =======================

__global__ __launch_bounds__(256, 2) void pn_layer_kernel(
    const float* __restrict__ X, const float* __restrict__ W, float* __restrict__ H)
{
    __shared__ __align__(16) char Xl[64 * 256 * 2];
    __shared__ __align__(16) char Wl[2][256 * 32 * 2];
    const int tid  = threadIdx.x;
    const int lane = tid & 63;
    const int wv   = tid >> 6;
    const int qw   = lane >> 4;
    const int r15  = lane & 15;
    const int n  = blockIdx.y;
    const int b0 = blockIdx.x * 64;
    const float* Wn = W + (size_t)n * WSTRIDE;
    {
        const float4* Xv = reinterpret_cast<const float4*>(X + (size_t)b0 * DDIM);
        #pragma unroll
        for (int it = 0; it < 16; ++it) {
            int idx4 = tid + it * 256;
            int r = idx4 >> 6, c4 = idx4 & 63;
            float4 v = Xv[r * 64 + c4];
            uint2 p;
            p.x = (unsigned)f2bf(v.x) | ((unsigned)f2bf(v.y) << 16);
            p.y = (unsigned)f2bf(v.z) | ((unsigned)f2bf(v.w) << 16);
            int byte = (r * 512 + c4 * 8) ^ ((r & 7) << 4);
            *reinterpret_cast<uint2*>(&Xl[byte]) = p;
        }
    }
    f32x4 acc[4][4];
    #pragma unroll
    for (int nf = 0; nf < 4; ++nf) {
        int j = wv * 64 + nf * 16 + r15;
        float vj = Wn[(size_t)j * WROW + 256] + Wn[65792 + j];
        #pragma unroll
        for (int m = 0; m < 4; ++m) acc[m][nf] = f32x4{vj, vj, vj, vj};
    }
    auto stageW = [&](int buf, int kk) {
        const int k0 = kk * 32;
        const int j  = tid;
        float t[32];
        #pragma unroll
        for (int k = 0; k < 32; ++k) t[k] = Wn[(size_t)(k0 + k) * WROW + j];
        char* Wb = Wl[buf];
        #pragma unroll
        for (int g = 0; g < 4; ++g) {
            unsigned int p0 = (unsigned)f2bf(t[g*8+0]) | ((unsigned)f2bf(t[g*8+1]) << 16);
            unsigned int p1 = (unsigned)f2bf(t[g*8+2]) | ((unsigned)f2bf(t[g*8+3]) << 16);
            unsigned int p2 = (unsigned)f2bf(t[g*8+4]) | ((unsigned)f2bf(t[g*8+5]) << 16);
            unsigned int p3 = (unsigned)f2bf(t[g*8+6]) | ((unsigned)f2bf(t[g*8+7]) << 16);
            int byte = (j * 64 + g * 16) ^ ((j & 7) << 4);
            *reinterpret_cast<uint4*>(&Wb[byte]) = make_uint4(p0, p1, p2, p3);
        }
    };
    auto computeK = [&](int buf, int kk) {
        char* Wb = Wl[buf];
        short8 a[4], bbf[4];
        #pragma unroll
        for (int m = 0; m < 4; ++m) {
            int row = m * 16 + r15;
            int byte = (row * 512 + kk * 64 + qw * 16) ^ ((row & 7) << 4);
            a[m] = *reinterpret_cast<short8*>(&Xl[byte]);
        }
        #pragma unroll
        for (int nf = 0; nf < 4; ++nf) {
            int j = wv * 64 + nf * 16 + r15;
            int byte = (j * 64 + qw * 16) ^ ((j & 7) << 4);
            bbf[nf] = *reinterpret_cast<short8*>(&Wb[byte]);
        }
        #pragma unroll
        for (int m = 0; m < 4; ++m)
            #pragma unroll
            for (int nf = 0; nf < 4; ++nf)
                acc[m][nf] = __builtin_amdgcn_mfma_f32_16x16x32_bf16(a[m], bbf[nf], acc[m][nf], 0, 0, 0);
    };
    stageW(0, 0);
    int cur = 0;
    #pragma unroll
    for (int kk = 0; kk < 8; ++kk) {
        __syncthreads();
        if (kk < 7) stageW(cur ^ 1, kk + 1);
        computeK(cur, kk);
        cur ^= 1;
    }
    float ps[16];
    #pragma unroll
    for (int i = 0; i < 16; ++i) ps[i] = 0.f;
    #pragma unroll
    for (int m = 0; m < 4; ++m)
        #pragma unroll
        for (int nf = 0; nf < 4; ++nf) {
            int j = wv * 64 + nf * 16 + r15;
            #pragma unroll
            for (int r = 0; r < 4; ++r) {
                int brow = m * 16 + qw * 4 + r;
                int byte = (brow * 512 + j * 2) ^ ((brow & 7) << 4);
                float xv = bf2f(*reinterpret_cast<unsigned short*>(&Xl[byte]));
                ps[m * 4 + r] += acc[m][nf][r] * xv;
            }
        }
    #pragma unroll
    for (int off = 1; off <= 8; off <<= 1)
        #pragma unroll
        for (int i = 0; i < 16; ++i) ps[i] += __shfl_xor(ps[i], off, 64);
    __syncthreads();
    float* red = reinterpret_cast<float*>(Wl);
    if (r15 == 0) {
        #pragma unroll
        for (int m = 0; m < 4; ++m)
            #pragma unroll
            for (int r = 0; r < 4; ++r)
                red[wv * 64 + m * 16 + qw * 4 + r] = ps[m * 4 + r];
    }
    __syncthreads();
    if (tid < 64) {
        float s = red[tid] + red[64 + tid] + red[128 + tid] + red[192 + tid] + Wn[66048];
        H[(size_t)(b0 + tid) * DDIM + n] = s;
    }
}

__global__ __launch_bounds__(256) void out_kernel(
    const float* __restrict__ H, const float* __restrict__ w_out,
    const float* __restrict__ b_out, float* __restrict__ out)
{
    int b = blockIdx.x * 4 + (threadIdx.x >> 6);
    int lane = threadIdx.x & 63;
    const float* h = H + (size_t)b * 256;
    float s = 0.f;
    #pragma unroll
    for (int c = 0; c < 4; ++c) s += h[lane + c * 64] * w_out[lane + c * 64];
    #pragma unroll
    for (int off = 1; off < 64; off <<= 1) s += __shfl_xor(s, off, 64);
    if (lane == 0) out[b] = s + b_out[0];
}

extern "C" void kernel_launch(void* const* d_in, const int* in_sizes, int n_in,
                              void* d_out, int out_size, void* d_ws, size_t ws_size,
                              hipStream_t stream) {
    const float* x    = (const float*)d_in[0];
    const float* W1   = (const float*)d_in[1];
    const float* W2   = (const float*)d_in[2];
    const float* W3   = (const float*)d_in[3];
    const float* wout = (const float*)d_in[4];
    const float* bout = (const float*)d_in[5];
    float* out = (float*)d_out;

    const size_t WT_BYTES  = (size_t)256 * 256 * 256 * 2;  // 33.55 MB
    const size_t XB_BYTES  = (size_t)2048 * 256 * 2;       // 1 MB
    const size_t XE2_BYTES = (size_t)32 * 16384 * 2;       // 1 MB
    const size_t VT_BYTES  = 256 * 256 * 4;                // 256 KB
    const size_t DV_BYTES  = 1024;
    const size_t HT_BYTES  = (size_t)256 * 2048 * 2;       // 1 MB (single buffer: pn never reads Ht)
    const size_t need = WT_BYTES + XB_BYTES + XE2_BYTES + VT_BYTES + DV_BYTES + HT_BYTES; // ~36.96 MB

    dim3 blk(256, 1, 1);

    if (ws_size >= need) {
        char* p = (char*)d_ws;
        unsigned short* Wt2 = (unsigned short*)p;              p += WT_BYTES;
        unsigned short* Xbf = (unsigned short*)p;              p += XB_BYTES;
        unsigned short* Xe2 = (unsigned short*)p;              p += XE2_BYTES;
        float*          Vt  = (float*)p;                       p += VT_BYTES;
        float*          Dv  = (float*)p;                       p += DV_BYTES;
        unsigned short* Ht  = (unsigned short*)p;

        const float* Ws[3] = {W1, W2, W3};

        dim3 wgrid(10, 256), lgrid(32, 64), xgrid(16);
        for (int L = 0; L < 3; ++L) {
            if (L == 0) conv_x_rm_kernel<<<xgrid, blk, 0, stream>>>(x, Xbf, Xe2);
            else        conv_x_tr_kernel<<<xgrid, blk, 0, stream>>>(Ht, Xbf, Xe2);
            conv_w2_kernel<<<wgrid, blk, 0, stream>>>(Ws[L], Wt2);
            conv_v_kernel<<<dim3(256), blk, 0, stream>>>(Ws[L], Vt, Dv);
            pn7_kernel<<<lgrid, blk, 0, stream>>>(Xbf, Xe2, Wt2, Vt, Dv, Ht);
        }
        out_tr_kernel<<<xgrid, blk, 0, stream>>>(Ht, wout, bout, out);
    } else {
        float* h1 = (float*)d_ws;
        float* h2 = h1 + 2048 * 256;
        dim3 grid(32, 256);
        pn_layer_kernel<<<grid, blk, 0, stream>>>(x,  W1, h1);
        pn_layer_kernel<<<grid, blk, 0, stream>>>(h1, W2, h2);
        pn_layer_kernel<<<grid, blk, 0, stream>>>(h2, W3, h1);
        out_kernel<<<512, blk, 0, stream>>>(h1, wout, bout, out);
    }
}

// Round 11
// 355.599 us; speedup vs baseline: 5.6941x; 1.0032x over previous
//
#include <hip/hip_runtime.h>
#include <hip/hip_bf16.h>

typedef __attribute__((ext_vector_type(8))) short short8;   // 8 bf16 (4 VGPRs) — MFMA A/B frag
typedef __attribute__((ext_vector_type(4))) float f32x4;    // MFMA C/D frag

#define DDIM 256
#define WROW 257
#define WSTRIDE 66049  // 257*257

__device__ __forceinline__ unsigned short f2bf(float f) {
    unsigned int u = __float_as_uint(f);
    u += 0x7fff + ((u >> 16) & 1);   // RNE (finite values)
    return (unsigned short)(u >> 16);
}
__device__ __forceinline__ float bf2f(unsigned short s) {
    return __uint_as_float(((unsigned int)s) << 16);
}

// ======================= FAST PATH =======================

// Symmetrized, pre-scaled, transposed W:
//   Wt2[n][j][k] = s * (A[k][j] + A[j][k]),  s = 1 for k32<j32, 0.5 for k32==j32
__global__ __launch_bounds__(256) void conv_w2_kernel(
    const float* __restrict__ Wf, unsigned short* __restrict__ Wt2)
{
    __shared__ float tKJ[64][65];
    __shared__ float tJK[64][65];
    const int TJ[10] = {0,1,1,2,2,2,3,3,3,3};
    const int TK[10] = {0,0,1,0,1,2,0,1,2,3};
    const int tid = threadIdx.x;
    const int n   = blockIdx.y;
    const int tj  = TJ[blockIdx.x];
    const int tk  = TK[blockIdx.x];
    const float* Wn = Wf + (size_t)n * WSTRIDE;
    #pragma unroll
    for (int it = 0; it < 16; ++it) {
        int r = it * 4 + (tid >> 6);
        int c = tid & 63;
        tKJ[r][c] = Wn[(size_t)(tk * 64 + r) * WROW + tj * 64 + c];
        tJK[r][c] = Wn[(size_t)(tj * 64 + r) * WROW + tk * 64 + c];
    }
    __syncthreads();
    unsigned short* out = Wt2 + ((size_t)n << 16);
    #pragma unroll
    for (int it = 0; it < 8; ++it) {
        int jl = it * 8 + (tid >> 5);
        int k2 = (tid & 31) * 2;
        int p32 = tk * 2 + (k2 >> 5);
        int q32 = tj * 2 + (jl >> 5);
        if (p32 <= q32) {
            float sc = (p32 == q32) ? 0.5f : 1.0f;
            float v0 = sc * (tKJ[k2][jl]     + tJK[jl][k2]);
            float v1 = sc * (tKJ[k2 + 1][jl] + tJK[jl][k2 + 1]);
            unsigned int u = (unsigned)f2bf(v0) | ((unsigned)f2bf(v1) << 16);
            *reinterpret_cast<unsigned int*>(out + (size_t)(tj * 64 + jl) * 256 + tk * 64 + k2) = u;
        }
    }
}

// Vt[n][j] = W[n][j][256] + W[n][256][j];  Dv[n] = W[n][256][256]
__global__ void conv_v_kernel(const float* __restrict__ Wf,
                              float* __restrict__ Vt, float* __restrict__ Dv)
{
    int n = blockIdx.x, j = threadIdx.x;
    const float* Wn = Wf + (size_t)n * WSTRIDE;
    Vt[n * 256 + j] = Wn[(size_t)j * WROW + 256] + Wn[65792 + j];
    if (j == 0) Dv[n] = Wn[66048];
}

// Epilogue gather: Xe2[bt][jt][m][lane] = short8 { x[row(m,qw,r)][jA] r=0..3, x[row][jB] r=0..3 }
//   jA = jt*32 + r15, jB = jA+16, row = m*16 + qw*4 + r (bt-local).  Lane-only-dependent.
__device__ __forceinline__ void xe_gather3(const unsigned short* T, unsigned short* Xe2,
                                           int bx, int tid) {
    const int lane = tid & 63, g = tid >> 6, qw = (tid >> 4) & 3, r15 = tid & 15;
    #pragma unroll
    for (int it = 0; it < 16; ++it) {
        int c  = g * 16 + it;        // flat (h, jt, m) in [0,64)
        int h  = c >> 5;
        int jt = (c >> 2) & 7;
        int m  = c & 3;
        int rbase = h * 64 + m * 16 + qw * 4;
        int jA = jt * 32 + r15;
        unsigned int u0 = T[(rbase + 0) * 256 + jA];
        unsigned int u1 = T[(rbase + 1) * 256 + jA];
        unsigned int u2 = T[(rbase + 2) * 256 + jA];
        unsigned int u3 = T[(rbase + 3) * 256 + jA];
        unsigned int v0 = T[(rbase + 0) * 256 + jA + 16];
        unsigned int v1 = T[(rbase + 1) * 256 + jA + 16];
        unsigned int v2 = T[(rbase + 2) * 256 + jA + 16];
        unsigned int v3 = T[(rbase + 3) * 256 + jA + 16];
        uint4 w = make_uint4(u0 | (u1 << 16), u2 | (u3 << 16),
                             v0 | (v1 << 16), v2 | (v3 << 16));
        *reinterpret_cast<uint4*>(Xe2 + ((size_t)(bx * 2 + h) * 16384 + jt * 2048 + m * 512 + lane * 8)) = w;
    }
}

// Layer-1 input prep: X f32 row-major -> Xbf (bf16 row-major) + Xe2
__global__ __launch_bounds__(256) void conv_x_rm_kernel(
    const float* __restrict__ X, unsigned short* __restrict__ Xbf, unsigned short* __restrict__ Xe2)
{
    __shared__ __align__(16) unsigned short T[128 * 256];
    const int tid = threadIdx.x;
    const int b0 = blockIdx.x * 128;
    const float4* Xv = reinterpret_cast<const float4*>(X + (size_t)b0 * 256);
    uint2* Xo = reinterpret_cast<uint2*>(Xbf + (size_t)b0 * 256);
    #pragma unroll
    for (int it = 0; it < 32; ++it) {
        int idx4 = it * 256 + tid;
        float4 v = Xv[idx4];
        uint2 p;
        p.x = (unsigned)f2bf(v.x) | ((unsigned)f2bf(v.y) << 16);
        p.y = (unsigned)f2bf(v.z) | ((unsigned)f2bf(v.w) << 16);
        *reinterpret_cast<uint2*>(&T[idx4 * 4]) = p;
        Xo[idx4] = p;
    }
    __syncthreads();
    xe_gather3(T, Xe2, blockIdx.x, tid);
}

// Layer-2/3 input prep: Ht bf16 [256][2048] (k-major) -> Xbf row-major + Xe2
__global__ __launch_bounds__(256) void conv_x_tr_kernel(
    const unsigned short* __restrict__ Hsrc, unsigned short* __restrict__ Xbf,
    unsigned short* __restrict__ Xe2)
{
    __shared__ __align__(16) unsigned short T[128 * 256];
    const int tid = threadIdx.x;
    const int b0 = blockIdx.x * 128;
    #pragma unroll
    for (int it = 0; it < 64; ++it) {
        int lin = it * 256 + tid;
        int k = lin >> 6, bp = lin & 63;
        unsigned int v = *reinterpret_cast<const unsigned int*>(Hsrc + (size_t)k * 2048 + b0 + bp * 2);
        T[(bp * 2) * 256 + k]     = (unsigned short)(v & 0xffff);
        T[(bp * 2 + 1) * 256 + k] = (unsigned short)(v >> 16);
    }
    __syncthreads();
    uint4* Xo = reinterpret_cast<uint4*>(Xbf + (size_t)b0 * 256);
    #pragma unroll
    for (int it = 0; it < 16; ++it) {   // 4096 uint4 per 128x256 tile
        int idx8 = it * 256 + tid;
        Xo[idx8] = *reinterpret_cast<uint4*>(&T[idx8 * 8]);
    }
    xe_gather3(T, Xe2, blockIdx.x, tid);
}

// pn8: block = 4 waves, BM=64; wave wv computes the FULL triangle for n = ng*4+wv.
// One barrier total; waves independent afterwards.
// R10 lesson kept: jt loop at unroll 1 (full unroll -> live-range explosion -> spill).
// R11: kk loop at unroll 2 (2-deep W prefetch window), branchless clamped prefetch,
// per-jt e-prefetch issued before the kk loop (latency hidden under MFMAs).
__global__ __launch_bounds__(256, 2) void pn8_kernel(
    const unsigned short* __restrict__ Xbf,  // [2048][256] bf16 row-major
    const unsigned short* __restrict__ Xe2,  // [32][8][4][64] short8 epilogue gather
    const unsigned short* __restrict__ Wt2,  // [256][256][256] bf16 symmetric triangle, j-major
    const float* __restrict__ Vt,            // [256][256] v
    const float* __restrict__ Dv,            // [256] d
    unsigned short* __restrict__ Ht)         // [256][2048] bf16
{
    __shared__ __align__(16) char Xl[32768];  // bf16 [64][256], XOR-swizzled

    const int tid  = threadIdx.x;
    const int lane = tid & 63;
    const int wv   = tid >> 6;
    const int qw   = lane >> 4;
    const int r15  = lane & 15;

    // fid -> (ng, bt): XCD k (fid%8) handles ng === k (mod 8) -> 32 n per XCD,
    // W working set ~2.3 MB < 4 MB L2, re-read by the 32 bt-blocks on that XCD.
    const int fid = blockIdx.y * 32 + blockIdx.x;
    const int bt  = (fid >> 3) & 31;
    const int ng  = (fid & 7) + ((fid >> 8) << 3);
    const int n   = ng * 4 + wv;
    const int b0  = bt * 64;

    // ---- stage bf16 X tile (32 KB) with write-side XOR swizzle ----
    {
        const uint4* xs = reinterpret_cast<const uint4*>(Xbf + (size_t)b0 * 256);
        #pragma unroll
        for (int c = 0; c < 8; ++c) {
            int idx = c * 256 + tid;
            uint4 v = xs[idx];
            int L = idx * 16;
            int d = L ^ (((L >> 9) & 7) << 4);
            *reinterpret_cast<uint4*>(&Xl[d]) = v;
        }
    }

    const unsigned short* Wn = Wt2 + ((size_t)n << 16);
    const float* vn = Vt + n * 256;
    const unsigned short* xe = Xe2 + (size_t)bt * 16384 + lane * 8;

    float ps[4][4];
    #pragma unroll
    for (int m = 0; m < 4; ++m)
        #pragma unroll
        for (int r = 0; r < 4; ++r) ps[m][r] = 0.f;

    __syncthreads();

    #pragma unroll 1   // DO NOT fully unroll (R9 spill); one jt per scheduling window
    for (int jt = 0; jt < 8; ++jt) {
        const unsigned short* pA = Wn + (size_t)(jt * 32 + r15) * 256 + qw * 8;
        const unsigned short* pB = pA + 16 * 256;
        const float vA = vn[jt * 32 + r15];
        const float vB = vn[jt * 32 + 16 + r15];
        short8 c0 = *reinterpret_cast<const short8*>(pA);
        short8 c1 = *reinterpret_cast<const short8*>(pB);
        // e-prefetch: consumed after the kk loop; latency hidden under the MFMAs
        short8 e0 = *reinterpret_cast<const short8*>(xe + jt * 2048 + 0 * 512);
        short8 e1 = *reinterpret_cast<const short8*>(xe + jt * 2048 + 1 * 512);
        short8 e2 = *reinterpret_cast<const short8*>(xe + jt * 2048 + 2 * 512);
        short8 e3 = *reinterpret_cast<const short8*>(xe + jt * 2048 + 3 * 512);

        f32x4 a0[4], a1[4];
        #pragma unroll
        for (int m = 0; m < 4; ++m) {
            a0[m] = f32x4{vA, vA, vA, vA};
            a1[m] = f32x4{vB, vB, vB, vB};
        }
        #pragma unroll 2   // 2-body window -> compiler hoists both bodies' W loads (2-deep prefetch)
        for (int kk = 0; kk <= jt; ++kk) {
            const int kn = (kk + 1 <= jt) ? kk + 1 : jt;   // wave-uniform clamp, branchless
            short8 nx0 = *reinterpret_cast<const short8*>(pA + kn * 32);
            short8 nx1 = *reinterpret_cast<const short8*>(pB + kn * 32);
            #pragma unroll
            for (int m = 0; m < 4; ++m) {
                const int row = m * 16 + r15;
                const int byte = (row * 512 + kk * 64 + qw * 16) ^ ((row & 7) << 4);
                short8 a = *reinterpret_cast<const short8*>(&Xl[byte]);
                a0[m] = __builtin_amdgcn_mfma_f32_16x16x32_bf16(a, c0, a0[m], 0, 0, 0);
                a1[m] = __builtin_amdgcn_mfma_f32_16x16x32_bf16(a, c1, a1[m], 0, 0, 0);
            }
            c0 = nx0; c1 = nx1;
        }
        // contraction: ps += C .* x  (j-cols of this jt)
        #pragma unroll
        for (int r = 0; r < 4; ++r) {
            ps[0][r] += a0[0][r] * bf2f((unsigned short)e0[r]) + a1[0][r] * bf2f((unsigned short)e0[4 + r]);
            ps[1][r] += a0[1][r] * bf2f((unsigned short)e1[r]) + a1[1][r] * bf2f((unsigned short)e1[4 + r]);
            ps[2][r] += a0[2][r] * bf2f((unsigned short)e2[r]) + a1[2][r] * bf2f((unsigned short)e2[4 + r]);
            ps[3][r] += a0[3][r] * bf2f((unsigned short)e3[r]) + a1[3][r] * bf2f((unsigned short)e3[4 + r]);
        }
    }

    // reduce over the 16 j-lanes (r15 bits)
    #pragma unroll
    for (int off = 1; off <= 8; off <<= 1)
        #pragma unroll
        for (int m = 0; m < 4; ++m)
            #pragma unroll
            for (int r = 0; r < 4; ++r) ps[m][r] += __shfl_xor(ps[m][r], off, 64);

    if (r15 == 0) {
        const float dn = Dv[n];
        #pragma unroll
        for (int m = 0; m < 4; ++m)
            #pragma unroll
            for (int r = 0; r < 4; ++r)
                Ht[(size_t)n * 2048 + b0 + m * 16 + qw * 4 + r] = f2bf(ps[m][r] + dn);
    }
}

__global__ __launch_bounds__(256) void out_tr_kernel(
    const unsigned short* __restrict__ H3, const float* __restrict__ w_out,
    const float* __restrict__ b_out, float* __restrict__ out)
{
    __shared__ float red2[256];
    const int tid = threadIdx.x;
    const int b = blockIdx.x * 128 + (tid & 127);
    const int half = tid >> 7;
    float s = 0.f;
    #pragma unroll 8
    for (int k = 0; k < 128; ++k) {
        int nn = half * 128 + k;
        s += bf2f(H3[(size_t)nn * 2048 + b]) * w_out[nn];
    }
    red2[tid] = s;
    __syncthreads();
    if (tid < 128) out[b] = red2[tid] + red2[tid + 128] + b_out[0];
}

// ======================= FALLBACK PATH (small ws) =======================

__global__ __launch_bounds__(256, 2) void pn_layer_kernel(
    const float* __restrict__ X, const float* __restrict__ W, float* __restrict__ H)
{
    __shared__ __align__(16) char Xl[64 * 256 * 2];
    __shared__ __align__(16) char Wl[2][256 * 32 * 2];
    const int tid  = threadIdx.x;
    const int lane = tid & 63;
    const int wv   = tid >> 6;
    const int qw   = lane >> 4;
    const int r15  = lane & 15;
    const int n  = blockIdx.y;
    const int b0 = blockIdx.x * 64;
    const float* Wn = W + (size_t)n * WSTRIDE;
    {
        const float4* Xv = reinterpret_cast<const float4*>(X + (size_t)b0 * DDIM);
        #pragma unroll
        for (int it = 0; it < 16; ++it) {
            int idx4 = tid + it * 256;
            int r = idx4 >> 6, c4 = idx4 & 63;
            float4 v = Xv[r * 64 + c4];
            uint2 p;
            p.x = (unsigned)f2bf(v.x) | ((unsigned)f2bf(v.y) << 16);
            p.y = (unsigned)f2bf(v.z) | ((unsigned)f2bf(v.w) << 16);
            int byte = (r * 512 + c4 * 8) ^ ((r & 7) << 4);
            *reinterpret_cast<uint2*>(&Xl[byte]) = p;
        }
    }
    f32x4 acc[4][4];
    #pragma unroll
    for (int nf = 0; nf < 4; ++nf) {
        int j = wv * 64 + nf * 16 + r15;
        float vj = Wn[(size_t)j * WROW + 256] + Wn[65792 + j];
        #pragma unroll
        for (int m = 0; m < 4; ++m) acc[m][nf] = f32x4{vj, vj, vj, vj};
    }
    auto stageW = [&](int buf, int kk) {
        const int k0 = kk * 32;
        const int j  = tid;
        float t[32];
        #pragma unroll
        for (int k = 0; k < 32; ++k) t[k] = Wn[(size_t)(k0 + k) * WROW + j];
        char* Wb = Wl[buf];
        #pragma unroll
        for (int g = 0; g < 4; ++g) {
            unsigned int p0 = (unsigned)f2bf(t[g*8+0]) | ((unsigned)f2bf(t[g*8+1]) << 16);
            unsigned int p1 = (unsigned)f2bf(t[g*8+2]) | ((unsigned)f2bf(t[g*8+3]) << 16);
            unsigned int p2 = (unsigned)f2bf(t[g*8+4]) | ((unsigned)f2bf(t[g*8+5]) << 16);
            unsigned int p3 = (unsigned)f2bf(t[g*8+6]) | ((unsigned)f2bf(t[g*8+7]) << 16);
            int byte = (j * 64 + g * 16) ^ ((j & 7) << 4);
            *reinterpret_cast<uint4*>(&Wb[byte]) = make_uint4(p0, p1, p2, p3);
        }
    };
    auto computeK = [&](int buf, int kk) {
        char* Wb = Wl[buf];
        short8 a[4], bbf[4];
        #pragma unroll
        for (int m = 0; m < 4; ++m) {
            int row = m * 16 + r15;
            int byte = (row * 512 + kk * 64 + qw * 16) ^ ((row & 7) << 4);
            a[m] = *reinterpret_cast<short8*>(&Xl[byte]);
        }
        #pragma unroll
        for (int nf = 0; nf < 4; ++nf) {
            int j = wv * 64 + nf * 16 + r15;
            int byte = (j * 64 + qw * 16) ^ ((j & 7) << 4);
            bbf[nf] = *reinterpret_cast<short8*>(&Wb[byte]);
        }
        #pragma unroll
        for (int m = 0; m < 4; ++m)
            #pragma unroll
            for (int nf = 0; nf < 4; ++nf)
                acc[m][nf] = __builtin_amdgcn_mfma_f32_16x16x32_bf16(a[m], bbf[nf], acc[m][nf], 0, 0, 0);
    };
    stageW(0, 0);
    int cur = 0;
    #pragma unroll
    for (int kk = 0; kk < 8; ++kk) {
        __syncthreads();
        if (kk < 7) stageW(cur ^ 1, kk + 1);
        computeK(cur, kk);
        cur ^= 1;
    }
    float ps[16];
    #pragma unroll
    for (int i = 0; i < 16; ++i) ps[i] = 0.f;
    #pragma unroll
    for (int m = 0; m < 4; ++m)
        #pragma unroll
        for (int nf = 0; nf < 4; ++nf) {
            int j = wv * 64 + nf * 16 + r15;
            #pragma unroll
            for (int r = 0; r < 4; ++r) {
                int brow = m * 16 + qw * 4 + r;
                int byte = (brow * 512 + j * 2) ^ ((brow & 7) << 4);
                float xv = bf2f(*reinterpret_cast<unsigned short*>(&Xl[byte]));
                ps[m * 4 + r] += acc[m][nf][r] * xv;
            }
        }
    #pragma unroll
    for (int off = 1; off <= 8; off <<= 1)
        #pragma unroll
        for (int i = 0; i < 16; ++i) ps[i] += __shfl_xor(ps[i], off, 64);
    __syncthreads();
    float* red = reinterpret_cast<float*>(Wl);
    if (r15 == 0) {
        #pragma unroll
        for (int m = 0; m < 4; ++m)
            #pragma unroll
            for (int r = 0; r < 4; ++r)
                red[wv * 64 + m * 16 + qw * 4 + r] = ps[m * 4 + r];
    }
    __syncthreads();
    if (tid < 64) {
        float s = red[tid] + red[64 + tid] + red[128 + tid] + red[192 + tid] + Wn[66048];
        H[(size_t)(b0 + tid) * DDIM + n] = s;
    }
}

__global__ __launch_bounds__(256) void out_kernel(
    const float* __restrict__ H, const float* __restrict__ w_out,
    const float* __restrict__ b_out, float* __restrict__ out)
{
    int b = blockIdx.x * 4 + (threadIdx.x >> 6);
    int lane = threadIdx.x & 63;
    const float* h = H + (size_t)b * 256;
    float s = 0.f;
    #pragma unroll
    for (int c = 0; c < 4; ++c) s += h[lane + c * 64] * w_out[lane + c * 64];
    #pragma unroll
    for (int off = 1; off < 64; off <<= 1) s += __shfl_xor(s, off, 64);
    if (lane == 0) out[b] = s + b_out[0];
}

extern "C" void kernel_launch(void* const* d_in, const int* in_sizes, int n_in,
                              void* d_out, int out_size, void* d_ws, size_t ws_size,
                              hipStream_t stream) {
    const float* x    = (const float*)d_in[0];
    const float* W1   = (const float*)d_in[1];
    const float* W2   = (const float*)d_in[2];
    const float* W3   = (const float*)d_in[3];
    const float* wout = (const float*)d_in[4];
    const float* bout = (const float*)d_in[5];
    float* out = (float*)d_out;

    const size_t WT_BYTES  = (size_t)256 * 256 * 256 * 2;  // 33.55 MB
    const size_t XB_BYTES  = (size_t)2048 * 256 * 2;       // 1 MB
    const size_t XE2_BYTES = (size_t)32 * 16384 * 2;       // 1 MB
    const size_t VT_BYTES  = 256 * 256 * 4;                // 256 KB
    const size_t DV_BYTES  = 1024;
    const size_t HT_BYTES  = (size_t)256 * 2048 * 2;       // 1 MB (single buffer: pn never reads Ht)
    const size_t need = WT_BYTES + XB_BYTES + XE2_BYTES + VT_BYTES + DV_BYTES + HT_BYTES; // ~36.96 MB

    dim3 blk(256, 1, 1);

    if (ws_size >= need) {
        char* p = (char*)d_ws;
        unsigned short* Wt2 = (unsigned short*)p;              p += WT_BYTES;
        unsigned short* Xbf = (unsigned short*)p;              p += XB_BYTES;
        unsigned short* Xe2 = (unsigned short*)p;              p += XE2_BYTES;
        float*          Vt  = (float*)p;                       p += VT_BYTES;
        float*          Dv  = (float*)p;                       p += DV_BYTES;
        unsigned short* Ht  = (unsigned short*)p;

        const float* Ws[3] = {W1, W2, W3};

        dim3 wgrid(10, 256), lgrid(32, 64), xgrid(16);
        for (int L = 0; L < 3; ++L) {
            if (L == 0) conv_x_rm_kernel<<<xgrid, blk, 0, stream>>>(x, Xbf, Xe2);
            else        conv_x_tr_kernel<<<xgrid, blk, 0, stream>>>(Ht, Xbf, Xe2);
            conv_w2_kernel<<<wgrid, blk, 0, stream>>>(Ws[L], Wt2);
            conv_v_kernel<<<dim3(256), blk, 0, stream>>>(Ws[L], Vt, Dv);
            pn8_kernel<<<lgrid, blk, 0, stream>>>(Xbf, Xe2, Wt2, Vt, Dv, Ht);
        }
        out_tr_kernel<<<xgrid, blk, 0, stream>>>(Ht, wout, bout, out);
    } else {
        float* h1 = (float*)d_ws;
        float* h2 = h1 + 2048 * 256;
        dim3 grid(32, 256);
        pn_layer_kernel<<<grid, blk, 0, stream>>>(x,  W1, h1);
        pn_layer_kernel<<<grid, blk, 0, stream>>>(h1, W2, h2);
        pn_layer_kernel<<<grid, blk, 0, stream>>>(h2, W3, h1);
        out_kernel<<<512, blk, 0, stream>>>(h1, wout, bout, out);
    }
}